// Round 1
// baseline (2333.667 us; speedup 1.0000x reference)
//
#include <hip/hip_runtime.h>
#include <math.h>

// Problem dims
#define TT   48
#define NAA  1024
#define NDD  1024
#define NBB  128
#define NTT  2176   // NAA+NDD+NBB
#define INF  16
#define HH   128
#define HTT  256
#define GG   768    // 3*HTT
#define OUTF 128
#define EAA  8192
#define EAD  8192
#define EDD  8192
#define EAB  2048
#define EDB  2048

// ---------------- workspace layout (in floats) ----------------
static const size_t SZ_P    = (size_t)TT * NTT * HH;     // 13,369,344
static const size_t OFF_P   = 0;
static const size_t OFF_Z   = OFF_P + SZ_P;
static const size_t OFF_TMP = OFF_Z + SZ_P;
static const size_t SZ_TMP  = (size_t)TT * 1024 * HH;    // 6,291,456
static const size_t OFF_H   = OFF_TMP + SZ_TMP;          // NTT*HTT
static const size_t OFF_POOL= OFF_H + (size_t)NTT * HTT;
static const size_t OFF_STATS = OFF_POOL + 1024;

// stats region word offsets (4B words from OFF_STATS)
enum {
  S_CNT_AA=0, S_CNT_DD=1024, S_CNT_AD=2048, S_CNT_AB=3072, S_CNT_DB=3200,
  S_CUR_AA=3328, S_CUR_DD=4352, S_CUR_AD=5376, S_CUR_AB=6400, S_CUR_DB=6528,
  S_ZERO_END=6656,   // [0, S_ZERO_END) must be zeroed each call
  S_OFF_AA=6656, S_OFF_DD=7684, S_OFF_AD=8712, S_OFF_AB=9740, S_OFF_DB=9872,
  S_SRC_AA=10004, S_SRC_DD=18196, S_SRC_AD=26388, S_SRC_AB=34580, S_SRC_DB=36628,
  S_NRM_AA=38676, S_NRM_DD=46868,
  S_DIS_AA=55060, S_DIS_DD=56084, S_INV_AD=57108, S_INV_AB=58132, S_INV_DB=58260,
  S_END=58388
};

// ---------------- CSR build ----------------
__global__ void count_kernel(const int* __restrict__ ei, int E, int* __restrict__ cnt) {
  int e = blockIdx.x * 256 + threadIdx.x;
  if (e < E) atomicAdd(&cnt[ei[E + e]], 1);
}

// single-block inclusive scan -> exclusive offs; also writes cursor copy and dis/inv
__global__ void scan_kernel(const int* __restrict__ cnt, int n,
                            int* __restrict__ offs, int* __restrict__ cur,
                            float* __restrict__ scale, int isGcn) {
  __shared__ int buf[1024];
  int i = threadIdx.x;
  int c = cnt[i];
  buf[i] = c;
  __syncthreads();
  for (int s = 1; s < n; s <<= 1) {
    int t = (i >= s) ? buf[i - s] : 0;
    __syncthreads();
    buf[i] += t;
    __syncthreads();
  }
  int excl = buf[i] - c;
  offs[i] = excl;
  cur[i]  = excl;
  if (i == n - 1) offs[n] = buf[i];
  if (isGcn) scale[i] = (c > 0) ? (1.0f / sqrtf((float)c)) : 0.0f;
  else       scale[i] = 1.0f / (float)(c > 0 ? c : 1);
}

__global__ void fill_kernel(const int* __restrict__ ei, int E, int* __restrict__ cur,
                            int* __restrict__ ssrc, float* __restrict__ snorm,
                            const float* __restrict__ dis) {
  int e = blockIdx.x * 256 + threadIdx.x;
  if (e >= E) return;
  int s = ei[e], d = ei[E + e];
  int pos = atomicAdd(&cur[d], 1);
  ssrc[pos] = s;
  if (snorm) snorm[pos] = dis[s] * dis[d];
}

// ---------------- projection (K=16) ----------------
__global__ __launch_bounds__(128) void proj_kernel(
    const float* __restrict__ xa, const float* __restrict__ xd, const float* __restrict__ xb,
    const float* __restrict__ Wpa, const float* __restrict__ bpa,
    const float* __restrict__ Wpd, const float* __restrict__ bpd,
    const float* __restrict__ Wpb, const float* __restrict__ bpb,
    float* __restrict__ P) {
  int b = blockIdx.x;
  int t = b / NTT, n = b % NTT;
  const float *x, *W, *bias;
  int row;
  if (n < 1024)      { x = xa; W = Wpa; bias = bpa; row = t * 1024 + n; }
  else if (n < 2048) { x = xd; W = Wpd; bias = bpd; row = t * 1024 + (n - 1024); }
  else               { x = xb; W = Wpb; bias = bpb; row = t * 128  + (n - 2048); }
  __shared__ float xr[16];
  if (threadIdx.x < 16) xr[threadIdx.x] = x[(size_t)row * 16 + threadIdx.x];
  __syncthreads();
  int c = threadIdx.x;
  float acc = bias[c];
#pragma unroll
  for (int k = 0; k < 16; ++k) acc = fmaf(xr[k], W[k * 128 + c], acc);
  P[((size_t)t * NTT + n) * 128 + c] = acc;
}

// ---------------- Z init with per-type bias sums ----------------
__global__ void zinit_kernel(float* __restrict__ Z,
    const float* __restrict__ bg_aa, const float* __restrict__ bg_dd, const float* __restrict__ bl_ad,
    const float* __restrict__ bl_ab, const float* __restrict__ bl_db) {
  size_t idx = (size_t)blockIdx.x * blockDim.x + threadIdx.x;
  size_t total = (size_t)TT * NTT * 128;
  size_t stride = (size_t)gridDim.x * blockDim.x;
  for (; idx < total; idx += stride) {
    int c = (int)(idx & 127);
    int n = (int)((idx >> 7) % NTT);
    float v;
    if (n < 1024)      v = bg_aa[c];
    else if (n < 2048) v = bg_dd[c] + bl_ad[c];
    else               v = bl_ab[c] + bl_db[c];
    Z[idx] = v;
  }
}

// ---------------- generic tiled fp32 matmul: C[M,128] (+)= A[M,128] @ B[128,128] ----------------
// row index mapping: physical_row(m) = (m>>shift)*stride + base + (m & mask)
__global__ __launch_bounds__(256) void matmul128(
    const float* __restrict__ A, const float* __restrict__ B, float* __restrict__ C,
    int shift, int aStride, int aBase, int cStride, int cBase, int accFlag) {
  __shared__ float As[32][68];   // transposed: As[k][r]
  __shared__ float Bs[32][132];  // Bs[k][c]
  const int tid = threadIdx.x;
  const int row0 = blockIdx.x * 64;
  const int mask = (1 << shift) - 1;

  float acc[8][4];
#pragma unroll
  for (int r = 0; r < 8; ++r)
#pragma unroll
    for (int c = 0; c < 4; ++c) acc[r][c] = 0.f;

  const int rA = tid >> 3;        // 0..31
  const int gA = tid & 7;         // k-group of 4
  const int cB = (tid & 31) * 4;
  const int kB = tid >> 5;        // 0..7
  const int r0 = (tid >> 5) * 8;
  const int c0 = (tid & 31) * 4;

  for (int kc = 0; kc < 4; ++kc) {
    int k0 = kc * 32;
#pragma unroll
    for (int i = 0; i < 2; ++i) {
      int r = rA + i * 32;
      int m = row0 + r;
      size_t arow = ((size_t)(m >> shift) * aStride + aBase + (m & mask)) * 128;
      float4 v = *(const float4*)(A + arow + k0 + gA * 4);
      As[gA * 4 + 0][r] = v.x; As[gA * 4 + 1][r] = v.y;
      As[gA * 4 + 2][r] = v.z; As[gA * 4 + 3][r] = v.w;
    }
#pragma unroll
    for (int i = 0; i < 4; ++i) {
      int kk = kB + i * 8;
      float4 v = *(const float4*)(B + (size_t)(k0 + kk) * 128 + cB);
      *(float4*)&Bs[kk][cB] = v;
    }
    __syncthreads();
#pragma unroll
    for (int kk = 0; kk < 32; ++kk) {
      float4 bv = *(const float4*)&Bs[kk][c0];
      float a[8];
      *(float4*)&a[0] = *(const float4*)&As[kk][r0];
      *(float4*)&a[4] = *(const float4*)&As[kk][r0 + 4];
#pragma unroll
      for (int r = 0; r < 8; ++r) {
        acc[r][0] = fmaf(a[r], bv.x, acc[r][0]);
        acc[r][1] = fmaf(a[r], bv.y, acc[r][1]);
        acc[r][2] = fmaf(a[r], bv.z, acc[r][2]);
        acc[r][3] = fmaf(a[r], bv.w, acc[r][3]);
      }
    }
    __syncthreads();
  }
#pragma unroll
  for (int r = 0; r < 8; ++r) {
    int m = row0 + r0 + r;
    size_t crow = ((size_t)(m >> shift) * cStride + cBase + (m & mask)) * 128;
    float4* cp = (float4*)(C + crow + c0);
    float4 v = make_float4(acc[r][0], acc[r][1], acc[r][2], acc[r][3]);
    if (accFlag) { float4 o = *cp; v.x += o.x; v.y += o.y; v.z += o.z; v.w += o.w; }
    *cp = v;
  }
}

// ---------------- GCN aggregate: Z[t, dstBase+d, :] += sum_e TMP[t, src_e, :] * norm_e ----------------
__global__ __launch_bounds__(128) void gcn_agg(
    const float* __restrict__ TMP, float* __restrict__ Z,
    const int* __restrict__ offs, const int* __restrict__ ssrc, const float* __restrict__ snorm,
    int nDst, int dstBase) {
  int b = blockIdx.x;
  int t = b / nDst, d = b % nDst;
  int e0 = offs[d], e1 = offs[d + 1];
  int c = threadIdx.x;
  float acc = 0.f;
  const float* base = TMP + (size_t)t * nDst * 128;   // square graph: nSrc == nDst
  for (int e = e0; e < e1; ++e) {
    int s = ssrc[e];
    float nm = snorm[e];
    acc = fmaf(base[(size_t)s * 128 + c], nm, acc);
  }
  Z[((size_t)t * NTT + dstBase + d) * 128 + c] += acc;
}

// ---------------- SAGE mean aggregate: TMPo[t,d,:] = mean_e P[t, srcBase+src_e, :] ----------------
__global__ __launch_bounds__(128) void sage_agg(
    const float* __restrict__ P, float* __restrict__ TMPo,
    const int* __restrict__ offs, const int* __restrict__ ssrc, const float* __restrict__ inv,
    int nDst, int srcBase) {
  int b = blockIdx.x;
  int t = b / nDst, d = b % nDst;
  int e0 = offs[d], e1 = offs[d + 1];
  int c = threadIdx.x;
  float acc = 0.f;
  const float* base = P + ((size_t)t * NTT + srcBase) * 128;
  for (int e = e0; e < e1; ++e) acc += base[(size_t)ssrc[e] * 128 + c];
  TMPo[((size_t)t * nDst + d) * 128 + c] = acc * inv[d];
}

// ---------------- fused GRU step (one launch per t) ----------------
__device__ __forceinline__ float sigmoidf_(float x) { return 1.0f / (1.0f + __expf(-x)); }

__global__ __launch_bounds__(256) void gru_step(
    const float* __restrict__ Z, int t,
    const float* __restrict__ Wi, const float* __restrict__ Wh,
    const float* __restrict__ bi, const float* __restrict__ bh,
    float* __restrict__ Hs) {
  int b = blockIdx.x;
  int n0, nr;
  if (b < 128) { n0 = b * 9; nr = 9; }
  else         { n0 = 1152 + (b - 128) * 8; nr = 8; }

  __shared__ float zl[9][128];
  __shared__ float hl[9][256];
  for (int idx = threadIdx.x; idx < nr * 128; idx += 256) {
    int r = idx >> 7, k = idx & 127;
    zl[r][k] = Z[((size_t)t * NTT + n0 + r) * 128 + k];
  }
  for (int idx = threadIdx.x; idx < nr * 256; idx += 256) {
    int r = idx >> 8, k = idx & 255;
    hl[r][k] = Hs[(size_t)(n0 + r) * 256 + k];
  }
  __syncthreads();

  int j = threadIdx.x;  // gate column 0..255
  float a0[9], a1[9], a2i[9], a2h[9];
#pragma unroll
  for (int r = 0; r < 9; ++r) { a0[r] = 0.f; a1[r] = 0.f; a2i[r] = 0.f; a2h[r] = 0.f; }

#pragma unroll 4
  for (int k = 0; k < 128; ++k) {
    float w0 = Wi[(size_t)k * GG + j];
    float w1 = Wi[(size_t)k * GG + 256 + j];
    float w2 = Wi[(size_t)k * GG + 512 + j];
#pragma unroll
    for (int r = 0; r < 9; ++r) {
      float a = zl[r][k];
      a0[r]  = fmaf(a, w0, a0[r]);
      a1[r]  = fmaf(a, w1, a1[r]);
      a2i[r] = fmaf(a, w2, a2i[r]);
    }
  }
#pragma unroll 4
  for (int k = 0; k < 256; ++k) {
    float w0 = Wh[(size_t)k * GG + j];
    float w1 = Wh[(size_t)k * GG + 256 + j];
    float w2 = Wh[(size_t)k * GG + 512 + j];
#pragma unroll
    for (int r = 0; r < 9; ++r) {
      float hv = hl[r][k];
      a0[r]  = fmaf(hv, w0, a0[r]);
      a1[r]  = fmaf(hv, w1, a1[r]);
      a2h[r] = fmaf(hv, w2, a2h[r]);
    }
  }

  float b0 = bi[j] + bh[j];
  float b1 = bi[256 + j] + bh[256 + j];
  float bi2 = bi[512 + j];
  float bh2 = bh[512 + j];
  for (int r = 0; r < nr; ++r) {
    float rr = sigmoidf_(a0[r] + b0);
    float zz = sigmoidf_(a1[r] + b1);
    float nn = tanhf(a2i[r] + bi2 + rr * (a2h[r] + bh2));
    float hold = hl[r][j];
    Hs[(size_t)(n0 + r) * 256 + j] = (1.f - zz) * nn + zz * hold;
  }
}

// ---------------- pooling + final projection ----------------
__global__ __launch_bounds__(256) void pool_kernel(const float* __restrict__ Hs, float* __restrict__ pooled) {
  int typ = blockIdx.x;
  int j = threadIdx.x;
  int base = (typ == 0) ? 0 : (typ == 1 ? 1024 : 2048);
  int nn = (typ == 2) ? 128 : 1024;
  float s = 0.f;
  for (int n = 0; n < nn; ++n) s += Hs[(size_t)(base + n) * 256 + j];
  pooled[typ * 256 + j] = s / (float)nn;
}

__global__ __launch_bounds__(128) void out_kernel(
    const float* __restrict__ pooled, const float* __restrict__ Wout,
    const float* __restrict__ bout, float* __restrict__ out) {
  int o = threadIdx.x;
  float acc = bout[o];
  for (int g = 0; g < GG; ++g) acc = fmaf(pooled[g], Wout[g * 128 + o], acc);
  out[o] = acc;
}

// ---------------- host launcher ----------------
extern "C" void kernel_launch(void* const* d_in, const int* in_sizes, int n_in,
                              void* d_out, int out_size, void* d_ws, size_t ws_size,
                              hipStream_t stream) {
  const float* xa    = (const float*)d_in[0];
  const float* xd    = (const float*)d_in[1];
  const float* xb    = (const float*)d_in[2];
  const int*   ei_aa = (const int*)d_in[3];
  const int*   ei_ad = (const int*)d_in[4];
  const int*   ei_dd = (const int*)d_in[5];
  const int*   ei_ab = (const int*)d_in[6];
  const int*   ei_db = (const int*)d_in[7];
  const float* Wp_a = (const float*)d_in[8];  const float* bp_a = (const float*)d_in[9];
  const float* Wp_d = (const float*)d_in[10]; const float* bp_d = (const float*)d_in[11];
  const float* Wp_b = (const float*)d_in[12]; const float* bp_b = (const float*)d_in[13];
  const float* Wg_aa = (const float*)d_in[14]; const float* bg_aa = (const float*)d_in[15];
  const float* Wg_dd = (const float*)d_in[16]; const float* bg_dd = (const float*)d_in[17];
  const float* Wl_ad = (const float*)d_in[18]; const float* Wr_ad = (const float*)d_in[19];
  const float* bl_ad = (const float*)d_in[20];
  const float* Wl_ab = (const float*)d_in[21]; const float* Wr_ab = (const float*)d_in[22];
  const float* bl_ab = (const float*)d_in[23];
  const float* Wl_db = (const float*)d_in[24]; const float* Wr_db = (const float*)d_in[25];
  const float* bl_db = (const float*)d_in[26];
  const float* Wi   = (const float*)d_in[27]; const float* Wh   = (const float*)d_in[28];
  const float* bi   = (const float*)d_in[29]; const float* bh   = (const float*)d_in[30];
  const float* Wout = (const float*)d_in[31]; const float* bout = (const float*)d_in[32];

  float* ws   = (float*)d_ws;
  float* P    = ws + OFF_P;
  float* Z    = ws + OFF_Z;
  float* TMP  = ws + OFF_TMP;
  float* Hbuf = ws + OFF_H;
  float* pooled = ws + OFF_POOL;
  int*   st   = (int*)(ws + OFF_STATS);
  float* stf  = (float*)st;

  // zero counters/cursors and h0
  hipMemsetAsync(st, 0, (size_t)S_ZERO_END * 4, stream);
  hipMemsetAsync(Hbuf, 0, (size_t)NTT * HTT * 4, stream);

  // --- CSR build for 5 relations ---
  count_kernel<<<(EAA + 255) / 256, 256, 0, stream>>>(ei_aa, EAA, st + S_CNT_AA);
  count_kernel<<<(EDD + 255) / 256, 256, 0, stream>>>(ei_dd, EDD, st + S_CNT_DD);
  count_kernel<<<(EAD + 255) / 256, 256, 0, stream>>>(ei_ad, EAD, st + S_CNT_AD);
  count_kernel<<<(EAB + 255) / 256, 256, 0, stream>>>(ei_ab, EAB, st + S_CNT_AB);
  count_kernel<<<(EDB + 255) / 256, 256, 0, stream>>>(ei_db, EDB, st + S_CNT_DB);

  scan_kernel<<<1, 1024, 0, stream>>>(st + S_CNT_AA, 1024, st + S_OFF_AA, st + S_CUR_AA, stf + S_DIS_AA, 1);
  scan_kernel<<<1, 1024, 0, stream>>>(st + S_CNT_DD, 1024, st + S_OFF_DD, st + S_CUR_DD, stf + S_DIS_DD, 1);
  scan_kernel<<<1, 1024, 0, stream>>>(st + S_CNT_AD, 1024, st + S_OFF_AD, st + S_CUR_AD, stf + S_INV_AD, 0);
  scan_kernel<<<1, 128, 0, stream>>>(st + S_CNT_AB, 128, st + S_OFF_AB, st + S_CUR_AB, stf + S_INV_AB, 0);
  scan_kernel<<<1, 128, 0, stream>>>(st + S_CNT_DB, 128, st + S_OFF_DB, st + S_CUR_DB, stf + S_INV_DB, 0);

  fill_kernel<<<(EAA + 255) / 256, 256, 0, stream>>>(ei_aa, EAA, st + S_CUR_AA, st + S_SRC_AA, stf + S_NRM_AA, stf + S_DIS_AA);
  fill_kernel<<<(EDD + 255) / 256, 256, 0, stream>>>(ei_dd, EDD, st + S_CUR_DD, st + S_SRC_DD, stf + S_NRM_DD, stf + S_DIS_DD);
  fill_kernel<<<(EAD + 255) / 256, 256, 0, stream>>>(ei_ad, EAD, st + S_CUR_AD, st + S_SRC_AD, nullptr, nullptr);
  fill_kernel<<<(EAB + 255) / 256, 256, 0, stream>>>(ei_ab, EAB, st + S_CUR_AB, st + S_SRC_AB, nullptr, nullptr);
  fill_kernel<<<(EDB + 255) / 256, 256, 0, stream>>>(ei_db, EDB, st + S_CUR_DB, st + S_SRC_DB, nullptr, nullptr);

  // --- projections into P[T, NTT, 128] ---
  proj_kernel<<<TT * NTT, 128, 0, stream>>>(xa, xd, xb, Wp_a, bp_a, Wp_d, bp_d, Wp_b, bp_b, P);

  // --- Z init with bias sums ---
  zinit_kernel<<<2048, 256, 0, stream>>>(Z, bg_aa, bg_dd, bl_ad, bl_ab, bl_db);

  const int M_big = TT * 1024;   // 49152 -> 768 tiles
  const int M_small = TT * 128;  // 6144  -> 96 tiles

  // GCN aa: TMP = P_A @ Wg_aa ; scatter into Z_A
  matmul128<<<M_big / 64, 256, 0, stream>>>(P, Wg_aa, TMP, 10, NTT, 0, 1024, 0, 0);
  gcn_agg<<<TT * 1024, 128, 0, stream>>>(TMP, Z, st + S_OFF_AA, st + S_SRC_AA, stf + S_NRM_AA, 1024, 0);

  // GCN dd: TMP = P_D @ Wg_dd ; scatter into Z_D
  matmul128<<<M_big / 64, 256, 0, stream>>>(P, Wg_dd, TMP, 10, NTT, 1024, 1024, 0, 0);
  gcn_agg<<<TT * 1024, 128, 0, stream>>>(TMP, Z, st + S_OFF_DD, st + S_SRC_DD, stf + S_NRM_DD, 1024, 1024);

  // SAGE ad: TMP = mean(P_A over edges) ; Z_D += TMP@Wl_ad ; Z_D += P_D@Wr_ad
  sage_agg<<<TT * 1024, 128, 0, stream>>>(P, TMP, st + S_OFF_AD, st + S_SRC_AD, stf + S_INV_AD, 1024, 0);
  matmul128<<<M_big / 64, 256, 0, stream>>>(TMP, Wl_ad, Z, 10, 1024, 0, NTT, 1024, 1);
  matmul128<<<M_big / 64, 256, 0, stream>>>(P, Wr_ad, Z, 10, NTT, 1024, NTT, 1024, 1);

  // SAGE ab
  sage_agg<<<TT * 128, 128, 0, stream>>>(P, TMP, st + S_OFF_AB, st + S_SRC_AB, stf + S_INV_AB, 128, 0);
  matmul128<<<M_small / 64, 256, 0, stream>>>(TMP, Wl_ab, Z, 7, 128, 0, NTT, 2048, 1);
  matmul128<<<M_small / 64, 256, 0, stream>>>(P, Wr_ab, Z, 7, NTT, 2048, NTT, 2048, 1);

  // SAGE db
  sage_agg<<<TT * 128, 128, 0, stream>>>(P, TMP, st + S_OFF_DB, st + S_SRC_DB, stf + S_INV_DB, 128, 1024);
  matmul128<<<M_small / 64, 256, 0, stream>>>(TMP, Wl_db, Z, 7, 128, 0, NTT, 2048, 1);
  matmul128<<<M_small / 64, 256, 0, stream>>>(P, Wr_db, Z, 7, NTT, 2048, NTT, 2048, 1);

  // --- GRU over 48 frames, h updated in place ---
  for (int t = 0; t < TT; ++t)
    gru_step<<<256, 256, 0, stream>>>(Z, t, Wi, Wh, bi, bh, Hbuf);

  // --- pool + output ---
  pool_kernel<<<3, 256, 0, stream>>>(Hbuf, pooled);
  out_kernel<<<1, 128, 0, stream>>>(pooled, Wout, bout, (float*)d_out);
}

// Round 2
// 1394.124 us; speedup vs baseline: 1.6739x; 1.6739x over previous
//
#include <hip/hip_runtime.h>
#include <math.h>

// Problem dims
#define TT   48
#define NAA  1024
#define NDD  1024
#define NBB  128
#define NTT  2176   // NAA+NDD+NBB
#define INF  16
#define HH   128
#define HTT  256
#define GG   768    // 3*HTT
#define OUTF 128
#define EAA  8192
#define EAD  8192
#define EDD  8192
#define EAB  2048
#define EDB  2048

typedef short bf16x8 __attribute__((ext_vector_type(8)));
typedef float f32x4  __attribute__((ext_vector_type(4)));

// ---------------- workspace layout (in floats) ----------------
static const size_t SZ_P    = (size_t)TT * NTT * HH;     // 13,369,344
static const size_t OFF_P   = 0;
// alias region inside P (used only AFTER the GNN phase, when P is dead):
static const size_t OFF_ZB  = OFF_P;                           // bf16 Z: 13,369,344 elems = 6,684,672 fl
static const size_t OFF_H0  = OFF_ZB + SZ_P / 2;               // bf16 h: 557,056 elems = 278,528 fl
static const size_t OFF_H1  = OFF_H0 + (size_t)NTT * HTT / 2;
static const size_t OFF_WCT = OFF_H1 + (size_t)NTT * HTT / 2;  // bf16 768x384 = 147,456 fl
static const size_t OFF_BA  = OFF_WCT + (size_t)GG * 384 / 2;  // 768 fl
static const size_t OFF_BB  = OFF_BA + GG;                     // 768 fl
// (alias end = 7,390,720 < SZ_P = 13,369,344  -> fits)
static const size_t OFF_Z   = OFF_P + SZ_P;
static const size_t OFF_TMP = OFF_Z + SZ_P;
static const size_t SZ_TMP  = (size_t)TT * 1024 * HH;    // 6,291,456
static const size_t OFF_POOL= OFF_TMP + SZ_TMP;          // 1024
static const size_t OFF_PART= OFF_POOL + 1024;           // 34*256 = 8704
static const size_t OFF_STATS = OFF_PART + 8704;

// stats region word offsets (4B words from OFF_STATS)
enum {
  S_CNT_AA=0, S_CNT_DD=1024, S_CNT_AD=2048, S_CNT_AB=3072, S_CNT_DB=3200,
  S_CUR_AA=3328, S_CUR_DD=4352, S_CUR_AD=5376, S_CUR_AB=6400, S_CUR_DB=6528,
  S_ZERO_END=6656,   // [0, S_ZERO_END) must be zeroed each call
  S_OFF_AA=6656, S_OFF_DD=7684, S_OFF_AD=8712, S_OFF_AB=9740, S_OFF_DB=9872,
  S_SRC_AA=10004, S_SRC_DD=18196, S_SRC_AD=26388, S_SRC_AB=34580, S_SRC_DB=36628,
  S_NRM_AA=38676, S_NRM_DD=46868,
  S_DIS_AA=55060, S_DIS_DD=56084, S_INV_AD=57108, S_INV_AB=58132, S_INV_DB=58260,
  S_END=58388
};

// ---------------- bf16 helpers ----------------
__device__ __forceinline__ unsigned short f2b(float x) {
  union { float f; unsigned int u; } v; v.f = x;
  unsigned int r = v.u + 0x7FFFu + ((v.u >> 16) & 1u);
  return (unsigned short)(r >> 16);
}
__device__ __forceinline__ float b2f(unsigned short b) {
  union { unsigned int u; float f; } v; v.u = ((unsigned int)b) << 16;
  return v.f;
}

// ---------------- CSR build ----------------
__global__ void count_kernel(const int* __restrict__ ei, int E, int* __restrict__ cnt) {
  int e = blockIdx.x * 256 + threadIdx.x;
  if (e < E) atomicAdd(&cnt[ei[E + e]], 1);
}

__global__ void scan_kernel(const int* __restrict__ cnt, int n,
                            int* __restrict__ offs, int* __restrict__ cur,
                            float* __restrict__ scale, int isGcn) {
  __shared__ int buf[1024];
  int i = threadIdx.x;
  int c = cnt[i];
  buf[i] = c;
  __syncthreads();
  for (int s = 1; s < n; s <<= 1) {
    int t = (i >= s) ? buf[i - s] : 0;
    __syncthreads();
    buf[i] += t;
    __syncthreads();
  }
  int excl = buf[i] - c;
  offs[i] = excl;
  cur[i]  = excl;
  if (i == n - 1) offs[n] = buf[i];
  if (isGcn) scale[i] = (c > 0) ? (1.0f / sqrtf((float)c)) : 0.0f;
  else       scale[i] = 1.0f / (float)(c > 0 ? c : 1);
}

__global__ void fill_kernel(const int* __restrict__ ei, int E, int* __restrict__ cur,
                            int* __restrict__ ssrc, float* __restrict__ snorm,
                            const float* __restrict__ dis) {
  int e = blockIdx.x * 256 + threadIdx.x;
  if (e >= E) return;
  int s = ei[e], d = ei[E + e];
  int pos = atomicAdd(&cur[d], 1);
  ssrc[pos] = s;
  if (snorm) snorm[pos] = dis[s] * dis[d];
}

// ---------------- projection (K=16) ----------------
__global__ __launch_bounds__(128) void proj_kernel(
    const float* __restrict__ xa, const float* __restrict__ xd, const float* __restrict__ xb,
    const float* __restrict__ Wpa, const float* __restrict__ bpa,
    const float* __restrict__ Wpd, const float* __restrict__ bpd,
    const float* __restrict__ Wpb, const float* __restrict__ bpb,
    float* __restrict__ P) {
  int b = blockIdx.x;
  int t = b / NTT, n = b % NTT;
  const float *x, *W, *bias;
  int row;
  if (n < 1024)      { x = xa; W = Wpa; bias = bpa; row = t * 1024 + n; }
  else if (n < 2048) { x = xd; W = Wpd; bias = bpd; row = t * 1024 + (n - 1024); }
  else               { x = xb; W = Wpb; bias = bpb; row = t * 128  + (n - 2048); }
  __shared__ float xr[16];
  if (threadIdx.x < 16) xr[threadIdx.x] = x[(size_t)row * 16 + threadIdx.x];
  __syncthreads();
  int c = threadIdx.x;
  float acc = bias[c];
#pragma unroll
  for (int k = 0; k < 16; ++k) acc = fmaf(xr[k], W[k * 128 + c], acc);
  P[((size_t)t * NTT + n) * 128 + c] = acc;
}

// ---------------- Z init with per-type bias sums ----------------
__global__ void zinit_kernel(float* __restrict__ Z,
    const float* __restrict__ bg_aa, const float* __restrict__ bg_dd, const float* __restrict__ bl_ad,
    const float* __restrict__ bl_ab, const float* __restrict__ bl_db) {
  size_t idx = (size_t)blockIdx.x * blockDim.x + threadIdx.x;
  size_t total = (size_t)TT * NTT * 128;
  size_t stride = (size_t)gridDim.x * blockDim.x;
  for (; idx < total; idx += stride) {
    int c = (int)(idx & 127);
    int n = (int)((idx >> 7) % NTT);
    float v;
    if (n < 1024)      v = bg_aa[c];
    else if (n < 2048) v = bg_dd[c] + bl_ad[c];
    else               v = bl_ab[c] + bl_db[c];
    Z[idx] = v;
  }
}

// ---------------- generic tiled fp32 matmul: C[M,128] (+)= A[M,128] @ B[128,128] ----------------
__global__ __launch_bounds__(256) void matmul128(
    const float* __restrict__ A, const float* __restrict__ B, float* __restrict__ C,
    int shift, int aStride, int aBase, int cStride, int cBase, int accFlag) {
  __shared__ float As[32][68];
  __shared__ float Bs[32][132];
  const int tid = threadIdx.x;
  const int row0 = blockIdx.x * 64;
  const int mask = (1 << shift) - 1;

  float acc[8][4];
#pragma unroll
  for (int r = 0; r < 8; ++r)
#pragma unroll
    for (int c = 0; c < 4; ++c) acc[r][c] = 0.f;

  const int rA = tid >> 3;
  const int gA = tid & 7;
  const int cB = (tid & 31) * 4;
  const int kB = tid >> 5;
  const int r0 = (tid >> 5) * 8;
  const int c0 = (tid & 31) * 4;

  for (int kc = 0; kc < 4; ++kc) {
    int k0 = kc * 32;
#pragma unroll
    for (int i = 0; i < 2; ++i) {
      int r = rA + i * 32;
      int m = row0 + r;
      size_t arow = ((size_t)(m >> shift) * aStride + aBase + (m & mask)) * 128;
      float4 v = *(const float4*)(A + arow + k0 + gA * 4);
      As[gA * 4 + 0][r] = v.x; As[gA * 4 + 1][r] = v.y;
      As[gA * 4 + 2][r] = v.z; As[gA * 4 + 3][r] = v.w;
    }
#pragma unroll
    for (int i = 0; i < 4; ++i) {
      int kk = kB + i * 8;
      float4 v = *(const float4*)(B + (size_t)(k0 + kk) * 128 + cB);
      *(float4*)&Bs[kk][cB] = v;
    }
    __syncthreads();
#pragma unroll
    for (int kk = 0; kk < 32; ++kk) {
      float4 bv = *(const float4*)&Bs[kk][c0];
      float a[8];
      *(float4*)&a[0] = *(const float4*)&As[kk][r0];
      *(float4*)&a[4] = *(const float4*)&As[kk][r0 + 4];
#pragma unroll
      for (int r = 0; r < 8; ++r) {
        acc[r][0] = fmaf(a[r], bv.x, acc[r][0]);
        acc[r][1] = fmaf(a[r], bv.y, acc[r][1]);
        acc[r][2] = fmaf(a[r], bv.z, acc[r][2]);
        acc[r][3] = fmaf(a[r], bv.w, acc[r][3]);
      }
    }
    __syncthreads();
  }
#pragma unroll
  for (int r = 0; r < 8; ++r) {
    int m = row0 + r0 + r;
    size_t crow = ((size_t)(m >> shift) * cStride + cBase + (m & mask)) * 128;
    float4* cp = (float4*)(C + crow + c0);
    float4 v = make_float4(acc[r][0], acc[r][1], acc[r][2], acc[r][3]);
    if (accFlag) { float4 o = *cp; v.x += o.x; v.y += o.y; v.z += o.z; v.w += o.w; }
    *cp = v;
  }
}

// ---------------- GCN aggregate ----------------
__global__ __launch_bounds__(128) void gcn_agg(
    const float* __restrict__ TMP, float* __restrict__ Z,
    const int* __restrict__ offs, const int* __restrict__ ssrc, const float* __restrict__ snorm,
    int nDst, int dstBase) {
  int b = blockIdx.x;
  int t = b / nDst, d = b % nDst;
  int e0 = offs[d], e1 = offs[d + 1];
  int c = threadIdx.x;
  float acc = 0.f;
  const float* base = TMP + (size_t)t * nDst * 128;
  for (int e = e0; e < e1; ++e) {
    int s = ssrc[e];
    float nm = snorm[e];
    acc = fmaf(base[(size_t)s * 128 + c], nm, acc);
  }
  Z[((size_t)t * NTT + dstBase + d) * 128 + c] += acc;
}

// ---------------- SAGE mean aggregate ----------------
__global__ __launch_bounds__(128) void sage_agg(
    const float* __restrict__ P, float* __restrict__ TMPo,
    const int* __restrict__ offs, const int* __restrict__ ssrc, const float* __restrict__ inv,
    int nDst, int srcBase) {
  int b = blockIdx.x;
  int t = b / nDst, d = b % nDst;
  int e0 = offs[d], e1 = offs[d + 1];
  int c = threadIdx.x;
  float acc = 0.f;
  const float* base = P + ((size_t)t * NTT + srcBase) * 128;
  for (int e = e0; e < e1; ++e) acc += base[(size_t)ssrc[e] * 128 + c];
  TMPo[((size_t)t * nDst + d) * 128 + c] = acc * inv[d];
}

// ---------------- GRU setup: permuted+transposed bf16 weights, fused biases ----------------
// WcT[p][k], p = gate-interleaved column: p = triple*48 + g*16 + cc
//   orig col = g*256 + triple*16 + cc; k<128 -> Wi, k>=128 -> Wh
__global__ __launch_bounds__(384) void wct_build(
    const float* __restrict__ Wi, const float* __restrict__ Wh,
    const float* __restrict__ bi, const float* __restrict__ bh,
    unsigned short* __restrict__ WcT, float* __restrict__ BA, float* __restrict__ BB) {
  int p = blockIdx.x;
  int k = threadIdx.x;
  int triple = p / 48, g = (p % 48) / 16, cc = p % 16;
  int orig = g * 256 + triple * 16 + cc;
  float w = (k < 128) ? Wi[(size_t)k * GG + orig] : Wh[(size_t)(k - 128) * GG + orig];
  WcT[(size_t)p * 384 + k] = f2b(w);
  if (k == 0) {
    BA[p] = (g < 2) ? (bi[orig] + bh[orig]) : bi[orig];
    BB[p] = bh[orig];
  }
}

// ---------------- Z fp32 -> bf16 ----------------
__global__ __launch_bounds__(256) void zb_convert(const float* __restrict__ Z,
                                                  unsigned short* __restrict__ Zb) {
  size_t base = ((size_t)blockIdx.x * 256 + threadIdx.x) * 4;
  float4 v = *(const float4*)(Z + base);
  unsigned short o[4] = { f2b(v.x), f2b(v.y), f2b(v.z), f2b(v.w) };
  *(uint2*)(Zb + base) = *(const uint2*)o;
}

// ---------------- MFMA GRU step ----------------
// grid: 68 row-blocks (32 rows) x 8 col-blocks (96 gate cols = 2 ctile-triples)
// wave (of 4): 16 rows x 48 gate cols (one r/z/n triple); no LDS.
__global__ __launch_bounds__(256) void gru_mfma(
    const unsigned short* __restrict__ Zb, int t,
    const unsigned short* __restrict__ WcT,
    const float* __restrict__ BA, const float* __restrict__ BB,
    const unsigned short* __restrict__ Hc, unsigned short* __restrict__ Hn) {
  int mb = blockIdx.x >> 3;          // 0..67
  int nb = blockIdx.x & 7;           // 0..7
  int w  = threadIdx.x >> 6;         // 0..3
  int lane = threadIdx.x & 63;
  int wm = w >> 1, wn = w & 1;
  int row0 = mb * 32 + wm * 16;      // wave's 16 rows
  int triple = nb * 2 + wn;          // 0..15
  int l15 = lane & 15;
  int lk  = (lane >> 4) * 8;         // k sub-offset

  f32x4 accR = {0.f, 0.f, 0.f, 0.f};
  f32x4 accZ = {0.f, 0.f, 0.f, 0.f};
  f32x4 accNi = {0.f, 0.f, 0.f, 0.f};
  f32x4 accNh = {0.f, 0.f, 0.f, 0.f};

  const unsigned short* zrow = Zb + (size_t)t * NTT * 128;
  int arow = row0 + l15;
  const unsigned short* wbase = WcT + (size_t)(triple * 48 + l15) * 384;

#pragma unroll
  for (int ks = 0; ks < 12; ++ks) {
    int k = ks * 32 + lk;
    const unsigned short* asrc = (ks < 4) ? (zrow + (size_t)arow * 128 + k)
                                          : (Hc + (size_t)arow * 256 + (k - 128));
    bf16x8 a  = *(const bf16x8*)asrc;
    bf16x8 br = *(const bf16x8*)(wbase + k);             // gate r cols
    bf16x8 bz = *(const bf16x8*)(wbase + 16 * 384 + k);  // gate z cols
    bf16x8 bn = *(const bf16x8*)(wbase + 32 * 384 + k);  // gate n cols
    accR = __builtin_amdgcn_mfma_f32_16x16x32_bf16(a, br, accR, 0, 0, 0);
    accZ = __builtin_amdgcn_mfma_f32_16x16x32_bf16(a, bz, accZ, 0, 0, 0);
    if (ks < 4) accNi = __builtin_amdgcn_mfma_f32_16x16x32_bf16(a, bn, accNi, 0, 0, 0);
    else        accNh = __builtin_amdgcn_mfma_f32_16x16x32_bf16(a, bn, accNh, 0, 0, 0);
  }

  // combine: C/D frag mapping col=lane&15, row=(lane>>4)*4+q (m89-verified)
  float bar = BA[triple * 48 + l15];
  float baz = BA[triple * 48 + 16 + l15];
  float ban = BA[triple * 48 + 32 + l15];
  float bbn = BB[triple * 48 + 32 + l15];
  int hc = triple * 16 + l15;
#pragma unroll
  for (int q = 0; q < 4; ++q) {
    int r = row0 + (lane >> 4) * 4 + q;
    float rr = 1.0f / (1.0f + __expf(-(accR[q] + bar)));
    float zz = 1.0f / (1.0f + __expf(-(accZ[q] + baz)));
    float nn = tanhf(accNi[q] + ban + rr * (accNh[q] + bbn));
    float ho = b2f(Hc[(size_t)r * 256 + hc]);
    Hn[(size_t)r * 256 + hc] = f2b((1.f - zz) * nn + zz * ho);
  }
}

// ---------------- pooling (two-stage) + final projection ----------------
__global__ __launch_bounds__(256) void pool_part(const unsigned short* __restrict__ Hb,
                                                 float* __restrict__ part) {
  int blk = blockIdx.x;   // 0..33, 64 nodes each
  int j = threadIdx.x;    // 0..255
  int base = blk * 64;
  float s = 0.f;
  for (int r = 0; r < 64; ++r) s += b2f(Hb[(size_t)(base + r) * 256 + j]);
  part[blk * 256 + j] = s;
}

__global__ __launch_bounds__(256) void pool_final(const float* __restrict__ part,
                                                  float* __restrict__ pooled) {
  int typ = blockIdx.x;
  int j = threadIdx.x;
  int b0 = (typ == 0) ? 0 : (typ == 1 ? 16 : 32);
  int b1 = (typ == 2) ? 34 : b0 + 16;
  float s = 0.f;
  for (int b = b0; b < b1; ++b) s += part[b * 256 + j];
  pooled[typ * 256 + j] = s / (float)((typ == 2) ? 128 : 1024);
}

__global__ __launch_bounds__(128) void out_kernel(
    const float* __restrict__ pooled, const float* __restrict__ Wout,
    const float* __restrict__ bout, float* __restrict__ out) {
  int o = threadIdx.x;
  float acc = bout[o];
  for (int g = 0; g < GG; ++g) acc = fmaf(pooled[g], Wout[g * 128 + o], acc);
  out[o] = acc;
}

// ---------------- host launcher ----------------
extern "C" void kernel_launch(void* const* d_in, const int* in_sizes, int n_in,
                              void* d_out, int out_size, void* d_ws, size_t ws_size,
                              hipStream_t stream) {
  const float* xa    = (const float*)d_in[0];
  const float* xd    = (const float*)d_in[1];
  const float* xb    = (const float*)d_in[2];
  const int*   ei_aa = (const int*)d_in[3];
  const int*   ei_ad = (const int*)d_in[4];
  const int*   ei_dd = (const int*)d_in[5];
  const int*   ei_ab = (const int*)d_in[6];
  const int*   ei_db = (const int*)d_in[7];
  const float* Wp_a = (const float*)d_in[8];  const float* bp_a = (const float*)d_in[9];
  const float* Wp_d = (const float*)d_in[10]; const float* bp_d = (const float*)d_in[11];
  const float* Wp_b = (const float*)d_in[12]; const float* bp_b = (const float*)d_in[13];
  const float* Wg_aa = (const float*)d_in[14]; const float* bg_aa = (const float*)d_in[15];
  const float* Wg_dd = (const float*)d_in[16]; const float* bg_dd = (const float*)d_in[17];
  const float* Wl_ad = (const float*)d_in[18]; const float* Wr_ad = (const float*)d_in[19];
  const float* bl_ad = (const float*)d_in[20];
  const float* Wl_ab = (const float*)d_in[21]; const float* Wr_ab = (const float*)d_in[22];
  const float* bl_ab = (const float*)d_in[23];
  const float* Wl_db = (const float*)d_in[24]; const float* Wr_db = (const float*)d_in[25];
  const float* bl_db = (const float*)d_in[26];
  const float* Wi   = (const float*)d_in[27]; const float* Wh   = (const float*)d_in[28];
  const float* bi   = (const float*)d_in[29]; const float* bh   = (const float*)d_in[30];
  const float* Wout = (const float*)d_in[31]; const float* bout = (const float*)d_in[32];

  float* ws   = (float*)d_ws;
  float* P    = ws + OFF_P;
  float* Z    = ws + OFF_Z;
  float* TMP  = ws + OFF_TMP;
  float* pooled = ws + OFF_POOL;
  float* part   = ws + OFF_PART;
  unsigned short* Zb  = (unsigned short*)(ws + OFF_ZB);
  unsigned short* H0  = (unsigned short*)(ws + OFF_H0);
  unsigned short* H1  = (unsigned short*)(ws + OFF_H1);
  unsigned short* WcT = (unsigned short*)(ws + OFF_WCT);
  float* BA = ws + OFF_BA;
  float* BB = ws + OFF_BB;
  int*   st  = (int*)(ws + OFF_STATS);
  float* stf = (float*)st;

  hipMemsetAsync(st, 0, (size_t)S_ZERO_END * 4, stream);

  // --- CSR build for 5 relations ---
  count_kernel<<<(EAA + 255) / 256, 256, 0, stream>>>(ei_aa, EAA, st + S_CNT_AA);
  count_kernel<<<(EDD + 255) / 256, 256, 0, stream>>>(ei_dd, EDD, st + S_CNT_DD);
  count_kernel<<<(EAD + 255) / 256, 256, 0, stream>>>(ei_ad, EAD, st + S_CNT_AD);
  count_kernel<<<(EAB + 255) / 256, 256, 0, stream>>>(ei_ab, EAB, st + S_CNT_AB);
  count_kernel<<<(EDB + 255) / 256, 256, 0, stream>>>(ei_db, EDB, st + S_CNT_DB);

  scan_kernel<<<1, 1024, 0, stream>>>(st + S_CNT_AA, 1024, st + S_OFF_AA, st + S_CUR_AA, stf + S_DIS_AA, 1);
  scan_kernel<<<1, 1024, 0, stream>>>(st + S_CNT_DD, 1024, st + S_OFF_DD, st + S_CUR_DD, stf + S_DIS_DD, 1);
  scan_kernel<<<1, 1024, 0, stream>>>(st + S_CNT_AD, 1024, st + S_OFF_AD, st + S_CUR_AD, stf + S_INV_AD, 0);
  scan_kernel<<<1, 128, 0, stream>>>(st + S_CNT_AB, 128, st + S_OFF_AB, st + S_CUR_AB, stf + S_INV_AB, 0);
  scan_kernel<<<1, 128, 0, stream>>>(st + S_CNT_DB, 128, st + S_OFF_DB, st + S_CUR_DB, stf + S_INV_DB, 0);

  fill_kernel<<<(EAA + 255) / 256, 256, 0, stream>>>(ei_aa, EAA, st + S_CUR_AA, st + S_SRC_AA, stf + S_NRM_AA, stf + S_DIS_AA);
  fill_kernel<<<(EDD + 255) / 256, 256, 0, stream>>>(ei_dd, EDD, st + S_CUR_DD, st + S_SRC_DD, stf + S_NRM_DD, stf + S_DIS_DD);
  fill_kernel<<<(EAD + 255) / 256, 256, 0, stream>>>(ei_ad, EAD, st + S_CUR_AD, st + S_SRC_AD, nullptr, nullptr);
  fill_kernel<<<(EAB + 255) / 256, 256, 0, stream>>>(ei_ab, EAB, st + S_CUR_AB, st + S_SRC_AB, nullptr, nullptr);
  fill_kernel<<<(EDB + 255) / 256, 256, 0, stream>>>(ei_db, EDB, st + S_CUR_DB, st + S_SRC_DB, nullptr, nullptr);

  // --- projections + Z init ---
  proj_kernel<<<TT * NTT, 128, 0, stream>>>(xa, xd, xb, Wp_a, bp_a, Wp_d, bp_d, Wp_b, bp_b, P);
  zinit_kernel<<<2048, 256, 0, stream>>>(Z, bg_aa, bg_dd, bl_ad, bl_ab, bl_db);

  const int M_big = TT * 1024;
  const int M_small = TT * 128;

  matmul128<<<M_big / 64, 256, 0, stream>>>(P, Wg_aa, TMP, 10, NTT, 0, 1024, 0, 0);
  gcn_agg<<<TT * 1024, 128, 0, stream>>>(TMP, Z, st + S_OFF_AA, st + S_SRC_AA, stf + S_NRM_AA, 1024, 0);

  matmul128<<<M_big / 64, 256, 0, stream>>>(P, Wg_dd, TMP, 10, NTT, 1024, 1024, 0, 0);
  gcn_agg<<<TT * 1024, 128, 0, stream>>>(TMP, Z, st + S_OFF_DD, st + S_SRC_DD, stf + S_NRM_DD, 1024, 1024);

  sage_agg<<<TT * 1024, 128, 0, stream>>>(P, TMP, st + S_OFF_AD, st + S_SRC_AD, stf + S_INV_AD, 1024, 0);
  matmul128<<<M_big / 64, 256, 0, stream>>>(TMP, Wl_ad, Z, 10, 1024, 0, NTT, 1024, 1);
  matmul128<<<M_big / 64, 256, 0, stream>>>(P, Wr_ad, Z, 10, NTT, 1024, NTT, 1024, 1);

  sage_agg<<<TT * 128, 128, 0, stream>>>(P, TMP, st + S_OFF_AB, st + S_SRC_AB, stf + S_INV_AB, 128, 0);
  matmul128<<<M_small / 64, 256, 0, stream>>>(TMP, Wl_ab, Z, 7, 128, 0, NTT, 2048, 1);
  matmul128<<<M_small / 64, 256, 0, stream>>>(P, Wr_ab, Z, 7, NTT, 2048, NTT, 2048, 1);

  sage_agg<<<TT * 128, 128, 0, stream>>>(P, TMP, st + S_OFF_DB, st + S_SRC_DB, stf + S_INV_DB, 128, 1024);
  matmul128<<<M_small / 64, 256, 0, stream>>>(TMP, Wl_db, Z, 7, 128, 0, NTT, 2048, 1);
  matmul128<<<M_small / 64, 256, 0, stream>>>(P, Wr_db, Z, 7, NTT, 2048, NTT, 2048, 1);

  // --- GRU setup (P is dead now; alias region becomes live) ---
  wct_build<<<GG, 384, 0, stream>>>(Wi, Wh, bi, bh, WcT, BA, BB);
  zb_convert<<<(int)(SZ_P / 4 / 256), 256, 0, stream>>>(Z, Zb);
  hipMemsetAsync(H0, 0, (size_t)NTT * HTT * 2, stream);

  // --- GRU over 48 frames, ping-pong h ---
  for (int t = 0; t < TT; ++t) {
    const unsigned short* hc = (t & 1) ? H1 : H0;
    unsigned short*       hn = (t & 1) ? H0 : H1;
    gru_mfma<<<68 * 8, 256, 0, stream>>>(Zb, t, WcT, BA, BB, hc, hn);
  }
  // T=48 even -> final h is in H0

  // --- pool + output ---
  pool_part<<<34, 256, 0, stream>>>(H0, part);
  pool_final<<<3, 256, 0, stream>>>(part, pooled);
  out_kernel<<<1, 128, 0, stream>>>(pooled, Wout, bout, (float*)d_out);
}

// Round 3
// 1198.103 us; speedup vs baseline: 1.9478x; 1.1636x over previous
//
#include <hip/hip_runtime.h>
#include <math.h>

// Problem dims
#define TT   48
#define NAA  1024
#define NDD  1024
#define NBB  128
#define NTT  2176   // NAA+NDD+NBB
#define INF  16
#define HH   128
#define HTT  256
#define GG   768    // 3*HTT
#define OUTF 128
#define EAA  8192
#define EAD  8192
#define EDD  8192
#define EAB  2048
#define EDB  2048

typedef short bf16x8 __attribute__((ext_vector_type(8)));
typedef float f32x4  __attribute__((ext_vector_type(4)));

// ---------------- workspace layout (in floats) ----------------
static const size_t SZ_PB   = (size_t)TT * NTT * HH;           // bf16 elem count 13,369,344
static const size_t OFF_PB  = 0;                               // bf16 P
static const size_t OFF_ZB  = OFF_PB + SZ_PB / 2;              // bf16 Z
static const size_t OFF_H0  = OFF_ZB + SZ_PB / 2;              // bf16 h ping
static const size_t OFF_H1  = OFF_H0 + (size_t)NTT * HTT / 2;  // bf16 h pong
static const size_t OFF_WCT = OFF_H1 + (size_t)NTT * HTT / 2;  // bf16 GRU weights 768x384
static const size_t OFF_BA  = OFF_WCT + (size_t)GG * 384 / 2;  // 768 fl
static const size_t OFF_BB  = OFF_BA + GG;                     // 768 fl
static const size_t OFF_WTG = OFF_BB + GG;                     // bf16 7x128x128 = 57,344 fl
static const size_t OFF_BT  = OFF_WTG + 57344;                 // 3x128 fl
static const size_t OFF_POOL= OFF_BT + 384;                    // 1024 fl
static const size_t OFF_PART= OFF_POOL + 1024;                 // 34*256 fl
static const size_t OFF_STATS = OFF_PART + 8704;

// stats region word offsets (4B words from OFF_STATS)
enum {
  S_CNT_AA=0, S_CNT_DD=1024, S_CNT_AD=2048, S_CNT_AB=3072, S_CNT_DB=3200,
  S_CUR_AA=3328, S_CUR_DD=4352, S_CUR_AD=5376, S_CUR_AB=6400, S_CUR_DB=6528,
  S_ZERO_END=6656,   // [0, S_ZERO_END) must be zeroed each call
  S_OFF_AA=6656, S_OFF_DD=7684, S_OFF_AD=8712, S_OFF_AB=9740, S_OFF_DB=9872,
  S_SRC_AA=10004, S_SRC_DD=18196, S_SRC_AD=26388, S_SRC_AB=34580, S_SRC_DB=36628,
  S_NRM_AA=38676, S_NRM_DD=46868,
  S_DIS_AA=55060, S_DIS_DD=56084, S_INV_AD=57108, S_INV_AB=58132, S_INV_DB=58260,
  S_END=58388
};

// ---------------- bf16 helpers ----------------
__device__ __forceinline__ unsigned short f2b(float x) {
  union { float f; unsigned int u; } v; v.f = x;
  unsigned int r = v.u + 0x7FFFu + ((v.u >> 16) & 1u);
  return (unsigned short)(r >> 16);
}
__device__ __forceinline__ float b2f(unsigned short b) {
  union { unsigned int u; float f; } v; v.u = ((unsigned int)b) << 16;
  return v.f;
}

// ---------------- CSR build ----------------
__global__ void count_kernel(const int* __restrict__ ei, int E, int* __restrict__ cnt) {
  int e = blockIdx.x * 256 + threadIdx.x;
  if (e < E) atomicAdd(&cnt[ei[E + e]], 1);
}

__global__ void scan_kernel(const int* __restrict__ cnt, int n,
                            int* __restrict__ offs, int* __restrict__ cur,
                            float* __restrict__ scale, int isGcn) {
  __shared__ int buf[1024];
  int i = threadIdx.x;
  int c = cnt[i];
  buf[i] = c;
  __syncthreads();
  for (int s = 1; s < n; s <<= 1) {
    int t = (i >= s) ? buf[i - s] : 0;
    __syncthreads();
    buf[i] += t;
    __syncthreads();
  }
  int excl = buf[i] - c;
  offs[i] = excl;
  cur[i]  = excl;
  if (i == n - 1) offs[n] = buf[i];
  if (isGcn) scale[i] = (c > 0) ? (1.0f / sqrtf((float)c)) : 0.0f;
  else       scale[i] = 1.0f / (float)(c > 0 ? c : 1);
}

__global__ void fill_kernel(const int* __restrict__ ei, int E, int* __restrict__ cur,
                            int* __restrict__ ssrc, float* __restrict__ snorm,
                            const float* __restrict__ dis) {
  int e = blockIdx.x * 256 + threadIdx.x;
  if (e >= E) return;
  int s = ei[e], d = ei[E + e];
  int pos = atomicAdd(&cur[d], 1);
  ssrc[pos] = s;
  if (snorm) snorm[pos] = dis[s] * dis[d];
}

// ---------------- projection (K=16) -> bf16 P ----------------
__global__ __launch_bounds__(128) void proj_kernel(
    const float* __restrict__ xa, const float* __restrict__ xd, const float* __restrict__ xb,
    const float* __restrict__ Wpa, const float* __restrict__ bpa,
    const float* __restrict__ Wpd, const float* __restrict__ bpd,
    const float* __restrict__ Wpb, const float* __restrict__ bpb,
    unsigned short* __restrict__ Pb) {
  int b = blockIdx.x;
  int t = b / NTT, n = b % NTT;
  const float *x, *W, *bias;
  int row;
  if (n < 1024)      { x = xa; W = Wpa; bias = bpa; row = t * 1024 + n; }
  else if (n < 2048) { x = xd; W = Wpd; bias = bpd; row = t * 1024 + (n - 1024); }
  else               { x = xb; W = Wpb; bias = bpb; row = t * 128  + (n - 2048); }
  __shared__ float xr[16];
  if (threadIdx.x < 16) xr[threadIdx.x] = x[(size_t)row * 16 + threadIdx.x];
  __syncthreads();
  int c = threadIdx.x;
  float acc = bias[c];
#pragma unroll
  for (int k = 0; k < 16; ++k) acc = fmaf(xr[k], W[k * 128 + c], acc);
  Pb[((size_t)t * NTT + n) * 128 + c] = f2b(acc);
}

// ---------------- GNN weight prep: WT[m][n][k] bf16 (m89-verified B layout) ----------------
__global__ __launch_bounds__(256) void gnn_wt_build(
    const float* __restrict__ Wg_aa, const float* __restrict__ Wg_dd,
    const float* __restrict__ Wl_ad, const float* __restrict__ Wr_ad,
    const float* __restrict__ Wl_ab, const float* __restrict__ Wl_db,
    const float* __restrict__ Wr_ab, const float* __restrict__ Wr_db,
    const float* __restrict__ bg_aa, const float* __restrict__ bg_dd,
    const float* __restrict__ bl_ad, const float* __restrict__ bl_ab,
    const float* __restrict__ bl_db,
    unsigned short* __restrict__ WTg, float* __restrict__ BT) {
  int m = blockIdx.x;
  const float* Ws[7] = {Wg_aa, Wg_dd, Wl_ad, Wr_ad, Wl_ab, Wl_db, Wr_ab};
  const float* W1 = Ws[m];
  for (int idx = threadIdx.x; idx < 16384; idx += 256) {
    int n = idx >> 7, k = idx & 127;
    float v = W1[k * 128 + n];
    if (m == 6) v += Wr_db[k * 128 + n];   // combined WrB = Wr_ab + Wr_db
    WTg[(size_t)m * 16384 + n * 128 + k] = f2b(v);
  }
  if (m == 0 && threadIdx.x < 128) {
    int n = threadIdx.x;
    BT[n]       = bg_aa[n];
    BT[128 + n] = bg_dd[n] + bl_ad[n];
    BT[256 + n] = bl_ab[n] + bl_db[n];
  }
}

// ---------------- fused GNN helpers ----------------
// gather one relation's aggregated input into AGG[64][136] bf16.
// thread tid: dst row tid>>2, 32-col chunk (tid&3)*32; fp32 accumulate.
__device__ __forceinline__ void gather_agg(
    const unsigned short* __restrict__ Psrc,   // Pb + (t*NTT + srcBase)*128
    const int* __restrict__ offs, const int* __restrict__ ssrc,
    const float* __restrict__ snorm,           // per-edge norm (GCN) or nullptr
    const float* __restrict__ inv,             // per-dst 1/deg (SAGE mean) or nullptr
    int dbase, unsigned short AGG[64][136], int tid) {
  int d_local = tid >> 2;
  int cg = (tid & 3) << 5;
  int d = dbase + d_local;
  int e0 = offs[d], e1 = offs[d + 1];
  float a[32];
#pragma unroll
  for (int j = 0; j < 32; ++j) a[j] = 0.f;
  const unsigned short* pbase = Psrc + cg;
  for (int e = e0; e < e1; ++e) {
    int s = ssrc[e];
    float sc = snorm ? snorm[e] : 1.0f;
    const unsigned short* pr = pbase + (size_t)s * 128;
#pragma unroll
    for (int c = 0; c < 4; ++c) {
      bf16x8 v = *(const bf16x8*)(pr + c * 8);
#pragma unroll
      for (int i = 0; i < 8; ++i)
        a[c * 8 + i] = fmaf(b2f((unsigned short)v[i]), sc, a[c * 8 + i]);
    }
  }
  float scale = inv ? inv[d] : 1.0f;
#pragma unroll
  for (int j = 0; j < 16; ++j) {
    unsigned int pk = (unsigned int)f2b(a[2 * j] * scale)
                    | ((unsigned int)f2b(a[2 * j + 1] * scale) << 16);
    *(unsigned int*)&AGG[d_local][cg + 2 * j] = pk;
  }
}

// MFMA: acc[f] += AGG_wave_rows @ WT  (A row=l&15, k=(l>>4)*8 — r2-verified)
__device__ __forceinline__ void mfma_agg(
    const unsigned short AGG[64][136], const unsigned short* __restrict__ wt,
    f32x4 acc[8], int w, int l15, int lk) {
#pragma unroll
  for (int ks = 0; ks < 4; ++ks) {
    int k = ks * 32 + lk;
    bf16x8 af = *(const bf16x8*)&AGG[w * 16 + l15][k];
#pragma unroll
    for (int f = 0; f < 8; ++f) {
      bf16x8 bfr = *(const bf16x8*)(wt + (size_t)(f * 16 + l15) * 128 + k);
      acc[f] = __builtin_amdgcn_mfma_f32_16x16x32_bf16(af, bfr, acc[f], 0, 0, 0);
    }
  }
}

// MFMA with A-rows straight from global Pb (dst's own features)
__device__ __forceinline__ void mfma_direct(
    const unsigned short* __restrict__ prow, const unsigned short* __restrict__ wt,
    f32x4 acc[8], int l15, int lk) {
#pragma unroll
  for (int ks = 0; ks < 4; ++ks) {
    int k = ks * 32 + lk;
    bf16x8 af = *(const bf16x8*)(prow + k);
#pragma unroll
    for (int f = 0; f < 8; ++f) {
      bf16x8 bfr = *(const bf16x8*)(wt + (size_t)(f * 16 + l15) * 128 + k);
      acc[f] = __builtin_amdgcn_mfma_f32_16x16x32_bf16(af, bfr, acc[f], 0, 0, 0);
    }
  }
}

// ---------------- fused GNN: per (frame, 64-row slice) block, writes Zb bf16 ----------------
__global__ __launch_bounds__(256) void gnn_fused(
    const unsigned short* __restrict__ Pb, unsigned short* __restrict__ Zb,
    const unsigned short* __restrict__ WTg, const float* __restrict__ BT,
    const int* __restrict__ st) {
  const float* stf = (const float*)st;
  int bid = blockIdx.x;
  int t = bid / 34, rb = bid % 34;
  int row0 = rb * 64;
  int tid = threadIdx.x;
  int w = tid >> 6, lane = tid & 63, l15 = lane & 15, lk = (lane >> 4) * 8;

  __shared__ unsigned short AGG[64][136];   // padded: row stride 68 words -> 2-way (free)

  int typ = (rb < 16) ? 0 : (rb < 32 ? 1 : 2);
  const float* bias = BT + typ * 128;
  f32x4 acc[8];
#pragma unroll
  for (int f = 0; f < 8; ++f) {
    float b = bias[f * 16 + l15];
    f32x4 bv = {b, b, b, b};
    acc[f] = bv;
  }

  const unsigned short* Pt = Pb + (size_t)t * NTT * 128;
  const unsigned short* prowD = Pt + (size_t)(row0 + w * 16 + l15) * 128;

  if (typ == 0) {
    // Z_A = gcn_aa(P_A) @ Wg_aa + bg_aa
    gather_agg(Pt, st + S_OFF_AA, st + S_SRC_AA, stf + S_NRM_AA, nullptr, row0, AGG, tid);
    __syncthreads();
    mfma_agg(AGG, WTg + 0 * 16384, acc, w, l15, lk);
  } else if (typ == 1) {
    int dbase = row0 - 1024;
    // Z_D = gcn_dd(P_D)@Wg_dd + mean_ad(P_A)@Wl_ad + P_D@Wr_ad + (bg_dd+bl_ad)
    gather_agg(Pt + 1024 * 128, st + S_OFF_DD, st + S_SRC_DD, stf + S_NRM_DD, nullptr, dbase, AGG, tid);
    __syncthreads();
    mfma_agg(AGG, WTg + 1 * 16384, acc, w, l15, lk);
    __syncthreads();
    gather_agg(Pt, st + S_OFF_AD, st + S_SRC_AD, nullptr, stf + S_INV_AD, dbase, AGG, tid);
    __syncthreads();
    mfma_agg(AGG, WTg + 2 * 16384, acc, w, l15, lk);
    mfma_direct(prowD, WTg + 3 * 16384, acc, l15, lk);
  } else {
    int dbase = row0 - 2048;
    // Z_B = mean_ab(P_A)@Wl_ab + mean_db(P_D)@Wl_db + P_B@(Wr_ab+Wr_db) + (bl_ab+bl_db)
    gather_agg(Pt, st + S_OFF_AB, st + S_SRC_AB, nullptr, stf + S_INV_AB, dbase, AGG, tid);
    __syncthreads();
    mfma_agg(AGG, WTg + 4 * 16384, acc, w, l15, lk);
    __syncthreads();
    gather_agg(Pt + 1024 * 128, st + S_OFF_DB, st + S_SRC_DB, nullptr, stf + S_INV_DB, dbase, AGG, tid);
    __syncthreads();
    mfma_agg(AGG, WTg + 5 * 16384, acc, w, l15, lk);
    mfma_direct(prowD, WTg + 6 * 16384, acc, l15, lk);
  }

  // stage bf16 output in LDS, then coalesced 16B stores
  __syncthreads();
#pragma unroll
  for (int f = 0; f < 8; ++f) {
#pragma unroll
    for (int q = 0; q < 4; ++q) {
      int rl = w * 16 + (lane >> 4) * 4 + q;    // C/D: col=l&15, row=(l>>4)*4+q
      AGG[rl][f * 16 + l15] = f2b(acc[f][q]);
    }
  }
  __syncthreads();
  unsigned short* zt = Zb + ((size_t)t * NTT + row0) * 128;
  for (int idx = tid; idx < 1024; idx += 256) {
    int r = idx >> 4, c = (idx & 15) << 3;
    *(uint4*)(zt + (size_t)r * 128 + c) = *(const uint4*)&AGG[r][c];
  }
}

// ---------------- GRU setup: permuted+transposed bf16 weights, fused biases ----------------
__global__ __launch_bounds__(384) void wct_build(
    const float* __restrict__ Wi, const float* __restrict__ Wh,
    const float* __restrict__ bi, const float* __restrict__ bh,
    unsigned short* __restrict__ WcT, float* __restrict__ BA, float* __restrict__ BB) {
  int p = blockIdx.x;
  int k = threadIdx.x;
  int triple = p / 48, g = (p % 48) / 16, cc = p % 16;
  int orig = g * 256 + triple * 16 + cc;
  float w = (k < 128) ? Wi[(size_t)k * GG + orig] : Wh[(size_t)(k - 128) * GG + orig];
  WcT[(size_t)p * 384 + k] = f2b(w);
  if (k == 0) {
    BA[p] = (g < 2) ? (bi[orig] + bh[orig]) : bi[orig];
    BB[p] = bh[orig];
  }
}

// ---------------- MFMA GRU step ----------------
__global__ __launch_bounds__(256) void gru_mfma(
    const unsigned short* __restrict__ Zb, int t,
    const unsigned short* __restrict__ WcT,
    const float* __restrict__ BA, const float* __restrict__ BB,
    const unsigned short* __restrict__ Hc, unsigned short* __restrict__ Hn) {
  int mb = blockIdx.x >> 3;
  int nb = blockIdx.x & 7;
  int w  = threadIdx.x >> 6;
  int lane = threadIdx.x & 63;
  int wm = w >> 1, wn = w & 1;
  int row0 = mb * 32 + wm * 16;
  int triple = nb * 2 + wn;
  int l15 = lane & 15;
  int lk  = (lane >> 4) * 8;

  f32x4 accR = {0.f, 0.f, 0.f, 0.f};
  f32x4 accZ = {0.f, 0.f, 0.f, 0.f};
  f32x4 accNi = {0.f, 0.f, 0.f, 0.f};
  f32x4 accNh = {0.f, 0.f, 0.f, 0.f};

  const unsigned short* zrow = Zb + (size_t)t * NTT * 128;
  int arow = row0 + l15;
  const unsigned short* wbase = WcT + (size_t)(triple * 48 + l15) * 384;

#pragma unroll
  for (int ks = 0; ks < 12; ++ks) {
    int k = ks * 32 + lk;
    const unsigned short* asrc = (ks < 4) ? (zrow + (size_t)arow * 128 + k)
                                          : (Hc + (size_t)arow * 256 + (k - 128));
    bf16x8 a  = *(const bf16x8*)asrc;
    bf16x8 br = *(const bf16x8*)(wbase + k);
    bf16x8 bz = *(const bf16x8*)(wbase + 16 * 384 + k);
    bf16x8 bn = *(const bf16x8*)(wbase + 32 * 384 + k);
    accR = __builtin_amdgcn_mfma_f32_16x16x32_bf16(a, br, accR, 0, 0, 0);
    accZ = __builtin_amdgcn_mfma_f32_16x16x32_bf16(a, bz, accZ, 0, 0, 0);
    if (ks < 4) accNi = __builtin_amdgcn_mfma_f32_16x16x32_bf16(a, bn, accNi, 0, 0, 0);
    else        accNh = __builtin_amdgcn_mfma_f32_16x16x32_bf16(a, bn, accNh, 0, 0, 0);
  }

  float bar = BA[triple * 48 + l15];
  float baz = BA[triple * 48 + 16 + l15];
  float ban = BA[triple * 48 + 32 + l15];
  float bbn = BB[triple * 48 + 32 + l15];
  int hc = triple * 16 + l15;
#pragma unroll
  for (int q = 0; q < 4; ++q) {
    int r = row0 + (lane >> 4) * 4 + q;
    float rr = 1.0f / (1.0f + __expf(-(accR[q] + bar)));
    float zz = 1.0f / (1.0f + __expf(-(accZ[q] + baz)));
    float nn = tanhf(accNi[q] + ban + rr * (accNh[q] + bbn));
    float ho = b2f(Hc[(size_t)r * 256 + hc]);
    Hn[(size_t)r * 256 + hc] = f2b((1.f - zz) * nn + zz * ho);
  }
}

// ---------------- pooling (two-stage) + final projection ----------------
__global__ __launch_bounds__(256) void pool_part(const unsigned short* __restrict__ Hb,
                                                 float* __restrict__ part) {
  int blk = blockIdx.x;
  int j = threadIdx.x;
  int base = blk * 64;
  float s = 0.f;
  for (int r = 0; r < 64; ++r) s += b2f(Hb[(size_t)(base + r) * 256 + j]);
  part[blk * 256 + j] = s;
}

__global__ __launch_bounds__(256) void pool_final(const float* __restrict__ part,
                                                  float* __restrict__ pooled) {
  int typ = blockIdx.x;
  int j = threadIdx.x;
  int b0 = (typ == 0) ? 0 : (typ == 1 ? 16 : 32);
  int b1 = (typ == 2) ? 34 : b0 + 16;
  float s = 0.f;
  for (int b = b0; b < b1; ++b) s += part[b * 256 + j];
  pooled[typ * 256 + j] = s / (float)((typ == 2) ? 128 : 1024);
}

__global__ __launch_bounds__(128) void out_kernel(
    const float* __restrict__ pooled, const float* __restrict__ Wout,
    const float* __restrict__ bout, float* __restrict__ out) {
  int o = threadIdx.x;
  float acc = bout[o];
  for (int g = 0; g < GG; ++g) acc = fmaf(pooled[g], Wout[g * 128 + o], acc);
  out[o] = acc;
}

// ---------------- host launcher ----------------
extern "C" void kernel_launch(void* const* d_in, const int* in_sizes, int n_in,
                              void* d_out, int out_size, void* d_ws, size_t ws_size,
                              hipStream_t stream) {
  const float* xa    = (const float*)d_in[0];
  const float* xd    = (const float*)d_in[1];
  const float* xb    = (const float*)d_in[2];
  const int*   ei_aa = (const int*)d_in[3];
  const int*   ei_ad = (const int*)d_in[4];
  const int*   ei_dd = (const int*)d_in[5];
  const int*   ei_ab = (const int*)d_in[6];
  const int*   ei_db = (const int*)d_in[7];
  const float* Wp_a = (const float*)d_in[8];  const float* bp_a = (const float*)d_in[9];
  const float* Wp_d = (const float*)d_in[10]; const float* bp_d = (const float*)d_in[11];
  const float* Wp_b = (const float*)d_in[12]; const float* bp_b = (const float*)d_in[13];
  const float* Wg_aa = (const float*)d_in[14]; const float* bg_aa = (const float*)d_in[15];
  const float* Wg_dd = (const float*)d_in[16]; const float* bg_dd = (const float*)d_in[17];
  const float* Wl_ad = (const float*)d_in[18]; const float* Wr_ad = (const float*)d_in[19];
  const float* bl_ad = (const float*)d_in[20];
  const float* Wl_ab = (const float*)d_in[21]; const float* Wr_ab = (const float*)d_in[22];
  const float* bl_ab = (const float*)d_in[23];
  const float* Wl_db = (const float*)d_in[24]; const float* Wr_db = (const float*)d_in[25];
  const float* bl_db = (const float*)d_in[26];
  const float* Wi   = (const float*)d_in[27]; const float* Wh   = (const float*)d_in[28];
  const float* bi   = (const float*)d_in[29]; const float* bh   = (const float*)d_in[30];
  const float* Wout = (const float*)d_in[31]; const float* bout = (const float*)d_in[32];

  float* ws   = (float*)d_ws;
  unsigned short* Pb  = (unsigned short*)(ws + OFF_PB);
  unsigned short* Zb  = (unsigned short*)(ws + OFF_ZB);
  unsigned short* H0  = (unsigned short*)(ws + OFF_H0);
  unsigned short* H1  = (unsigned short*)(ws + OFF_H1);
  unsigned short* WcT = (unsigned short*)(ws + OFF_WCT);
  float* BA = ws + OFF_BA;
  float* BB = ws + OFF_BB;
  unsigned short* WTg = (unsigned short*)(ws + OFF_WTG);
  float* BT = ws + OFF_BT;
  float* pooled = ws + OFF_POOL;
  float* part   = ws + OFF_PART;
  int*   st  = (int*)(ws + OFF_STATS);
  float* stf = (float*)st;

  hipMemsetAsync(st, 0, (size_t)S_ZERO_END * 4, stream);

  // --- CSR build for 5 relations ---
  count_kernel<<<(EAA + 255) / 256, 256, 0, stream>>>(ei_aa, EAA, st + S_CNT_AA);
  count_kernel<<<(EDD + 255) / 256, 256, 0, stream>>>(ei_dd, EDD, st + S_CNT_DD);
  count_kernel<<<(EAD + 255) / 256, 256, 0, stream>>>(ei_ad, EAD, st + S_CNT_AD);
  count_kernel<<<(EAB + 255) / 256, 256, 0, stream>>>(ei_ab, EAB, st + S_CNT_AB);
  count_kernel<<<(EDB + 255) / 256, 256, 0, stream>>>(ei_db, EDB, st + S_CNT_DB);

  scan_kernel<<<1, 1024, 0, stream>>>(st + S_CNT_AA, 1024, st + S_OFF_AA, st + S_CUR_AA, stf + S_DIS_AA, 1);
  scan_kernel<<<1, 1024, 0, stream>>>(st + S_CNT_DD, 1024, st + S_OFF_DD, st + S_CUR_DD, stf + S_DIS_DD, 1);
  scan_kernel<<<1, 1024, 0, stream>>>(st + S_CNT_AD, 1024, st + S_OFF_AD, st + S_CUR_AD, stf + S_INV_AD, 0);
  scan_kernel<<<1, 128, 0, stream>>>(st + S_CNT_AB, 128, st + S_OFF_AB, st + S_CUR_AB, stf + S_INV_AB, 0);
  scan_kernel<<<1, 128, 0, stream>>>(st + S_CNT_DB, 128, st + S_OFF_DB, st + S_CUR_DB, stf + S_INV_DB, 0);

  fill_kernel<<<(EAA + 255) / 256, 256, 0, stream>>>(ei_aa, EAA, st + S_CUR_AA, st + S_SRC_AA, stf + S_NRM_AA, stf + S_DIS_AA);
  fill_kernel<<<(EDD + 255) / 256, 256, 0, stream>>>(ei_dd, EDD, st + S_CUR_DD, st + S_SRC_DD, stf + S_NRM_DD, stf + S_DIS_DD);
  fill_kernel<<<(EAD + 255) / 256, 256, 0, stream>>>(ei_ad, EAD, st + S_CUR_AD, st + S_SRC_AD, nullptr, nullptr);
  fill_kernel<<<(EAB + 255) / 256, 256, 0, stream>>>(ei_ab, EAB, st + S_CUR_AB, st + S_SRC_AB, nullptr, nullptr);
  fill_kernel<<<(EDB + 255) / 256, 256, 0, stream>>>(ei_db, EDB, st + S_CUR_DB, st + S_SRC_DB, nullptr, nullptr);

  // --- projections (bf16) + weight prep ---
  proj_kernel<<<TT * NTT, 128, 0, stream>>>(xa, xd, xb, Wp_a, bp_a, Wp_d, bp_d, Wp_b, bp_b, Pb);
  gnn_wt_build<<<7, 256, 0, stream>>>(Wg_aa, Wg_dd, Wl_ad, Wr_ad, Wl_ab, Wl_db, Wr_ab, Wr_db,
                                      bg_aa, bg_dd, bl_ad, bl_ab, bl_db, WTg, BT);
  wct_build<<<GG, 384, 0, stream>>>(Wi, Wh, bi, bh, WcT, BA, BB);

  // --- fused GNN: Pb -> Zb directly ---
  gnn_fused<<<TT * 34, 256, 0, stream>>>(Pb, Zb, WTg, BT, st);

  // --- GRU over 48 frames, ping-pong h ---
  hipMemsetAsync(H0, 0, (size_t)NTT * HTT * 2, stream);
  for (int t = 0; t < TT; ++t) {
    const unsigned short* hc = (t & 1) ? H1 : H0;
    unsigned short*       hn = (t & 1) ? H0 : H1;
    gru_mfma<<<68 * 8, 256, 0, stream>>>(Zb, t, WcT, BA, BB, hc, hn);
  }
  // T=48 even -> final h is in H0

  // --- pool + output ---
  pool_part<<<34, 256, 0, stream>>>(H0, part);
  pool_final<<<3, 256, 0, stream>>>(part, pooled);
  out_kernel<<<1, 128, 0, stream>>>(pooled, Wout, bout, (float*)d_out);
}

// Round 4
// 699.478 us; speedup vs baseline: 3.3363x; 1.7129x over previous
//
#include <hip/hip_runtime.h>
#include <math.h>

// Problem dims
#define TT   48
#define NAA  1024
#define NDD  1024
#define NBB  128
#define NTT  2176   // NAA+NDD+NBB
#define INF  16
#define HH   128
#define HTT  256
#define GG   768    // 3*HTT
#define OUTF 128
#define EAA  8192
#define EAD  8192
#define EDD  8192
#define EAB  2048
#define EDB  2048
#define NEDGE (EAA + EDD + EAD + EAB + EDB)   // 28672

typedef short bf16x8 __attribute__((ext_vector_type(8)));
typedef float f32x4  __attribute__((ext_vector_type(4)));

// ---------------- workspace layout (in floats) ----------------
static const size_t SZ_PB   = (size_t)TT * NTT * HH;           // bf16 elem count 13,369,344
static const size_t OFF_PB  = 0;                               // bf16 P
static const size_t OFF_ZB  = OFF_PB + SZ_PB / 2;              // bf16 Z
static const size_t OFF_H0  = OFF_ZB + SZ_PB / 2;              // bf16 final h
static const size_t OFF_WCT = OFF_H0 + (size_t)NTT * HTT / 2;  // bf16 GRU weights 768x384
static const size_t OFF_BA  = OFF_WCT + (size_t)GG * 384 / 2;  // 768 fl
static const size_t OFF_BB  = OFF_BA + GG;                     // 768 fl
static const size_t OFF_WTG = OFF_BB + GG;                     // bf16 7x128x128 = 57,344 fl
static const size_t OFF_BT  = OFF_WTG + 57344;                 // 3x128 fl
static const size_t OFF_POOL= OFF_BT + 384;                    // 1024 fl
static const size_t OFF_PART= OFF_POOL + 1024;                 // 34*256 fl
static const size_t OFF_STATS = OFF_PART + 8704;

// stats region word offsets (4B words from OFF_STATS)
enum {
  S_CNT_AA=0, S_CNT_DD=1024, S_CNT_AD=2048, S_CNT_AB=3072, S_CNT_DB=3200,
  S_CUR_AA=3328, S_CUR_DD=4352, S_CUR_AD=5376, S_CUR_AB=6400, S_CUR_DB=6528,
  S_ZERO_END=6656,   // [0, S_ZERO_END) must be zeroed each call
  S_OFF_AA=6656, S_OFF_DD=7684, S_OFF_AD=8712, S_OFF_AB=9740, S_OFF_DB=9872,
  S_SRC_AA=10004, S_SRC_DD=18196, S_SRC_AD=26388, S_SRC_AB=34580, S_SRC_DB=36628,
  S_NRM_AA=38676, S_NRM_DD=46868,
  S_DIS_AA=55060, S_DIS_DD=56084, S_INV_AD=57108, S_INV_AB=58132, S_INV_DB=58260,
  S_END=58388
};

// ---------------- bf16 helpers ----------------
__device__ __forceinline__ unsigned short f2b(float x) {
  union { float f; unsigned int u; } v; v.f = x;
  unsigned int r = v.u + 0x7FFFu + ((v.u >> 16) & 1u);
  return (unsigned short)(r >> 16);
}
__device__ __forceinline__ float b2f(unsigned short b) {
  union { unsigned int u; float f; } v; v.u = ((unsigned int)b) << 16;
  return v.f;
}

// ---------------- CSR build (merged) ----------------
__global__ void count_all(const int* __restrict__ aa, const int* __restrict__ dd,
                          const int* __restrict__ ad, const int* __restrict__ ab,
                          const int* __restrict__ db, int* __restrict__ st) {
  int e = blockIdx.x * 256 + threadIdx.x;
  if (e < EAA) atomicAdd(&st[S_CNT_AA + aa[EAA + e]], 1);
  else if (e < EAA + EDD) atomicAdd(&st[S_CNT_DD + dd[EDD + (e - EAA)]], 1);
  else if (e < EAA + EDD + EAD) atomicAdd(&st[S_CNT_AD + ad[EAD + (e - EAA - EDD)]], 1);
  else if (e < EAA + EDD + EAD + EAB) atomicAdd(&st[S_CNT_AB + ab[EAB + (e - EAA - EDD - EAD)]], 1);
  else if (e < NEDGE) atomicAdd(&st[S_CNT_DB + db[EDB + (e - EAA - EDD - EAD - EAB)]], 1);
}

__global__ __launch_bounds__(1024) void scan5(int* __restrict__ st) {
  __shared__ int buf[1024];
  int b = blockIdx.x, i = threadIdx.x;
  int n, coff, ooff, uoff, soff, isGcn;
  switch (b) {
    case 0:  n = 1024; coff = S_CNT_AA; ooff = S_OFF_AA; uoff = S_CUR_AA; soff = S_DIS_AA; isGcn = 1; break;
    case 1:  n = 1024; coff = S_CNT_DD; ooff = S_OFF_DD; uoff = S_CUR_DD; soff = S_DIS_DD; isGcn = 1; break;
    case 2:  n = 1024; coff = S_CNT_AD; ooff = S_OFF_AD; uoff = S_CUR_AD; soff = S_INV_AD; isGcn = 0; break;
    case 3:  n = 128;  coff = S_CNT_AB; ooff = S_OFF_AB; uoff = S_CUR_AB; soff = S_INV_AB; isGcn = 0; break;
    default: n = 128;  coff = S_CNT_DB; ooff = S_OFF_DB; uoff = S_CUR_DB; soff = S_INV_DB; isGcn = 0; break;
  }
  float* stf = (float*)st;
  int c = (i < n) ? st[coff + i] : 0;
  buf[i] = c;
  __syncthreads();
  for (int s = 1; s < 1024; s <<= 1) {
    int tv = (i >= s) ? buf[i - s] : 0;
    __syncthreads();
    buf[i] += tv;
    __syncthreads();
  }
  if (i < n) {
    int excl = buf[i] - c;
    st[ooff + i] = excl;
    st[uoff + i] = excl;
    if (i == n - 1) st[ooff + n] = buf[i];
    if (isGcn) stf[soff + i] = (c > 0) ? (1.0f / sqrtf((float)c)) : 0.0f;
    else       stf[soff + i] = 1.0f / (float)(c > 0 ? c : 1);
  }
}

__global__ void fill_all(const int* __restrict__ aa, const int* __restrict__ dd,
                         const int* __restrict__ ad, const int* __restrict__ ab,
                         const int* __restrict__ db, int* __restrict__ st) {
  float* stf = (float*)st;
  int e = blockIdx.x * 256 + threadIdx.x;
  if (e < EAA) {
    int s = aa[e], d = aa[EAA + e];
    int pos = atomicAdd(&st[S_CUR_AA + d], 1);
    st[S_SRC_AA + pos] = s;
    stf[S_NRM_AA + pos] = stf[S_DIS_AA + s] * stf[S_DIS_AA + d];
  } else if (e < EAA + EDD) {
    int i = e - EAA;
    int s = dd[i], d = dd[EDD + i];
    int pos = atomicAdd(&st[S_CUR_DD + d], 1);
    st[S_SRC_DD + pos] = s;
    stf[S_NRM_DD + pos] = stf[S_DIS_DD + s] * stf[S_DIS_DD + d];
  } else if (e < EAA + EDD + EAD) {
    int i = e - EAA - EDD;
    int s = ad[i], d = ad[EAD + i];
    int pos = atomicAdd(&st[S_CUR_AD + d], 1);
    st[S_SRC_AD + pos] = s;
  } else if (e < EAA + EDD + EAD + EAB) {
    int i = e - EAA - EDD - EAD;
    int s = ab[i], d = ab[EAB + i];
    int pos = atomicAdd(&st[S_CUR_AB + d], 1);
    st[S_SRC_AB + pos] = s;
  } else if (e < NEDGE) {
    int i = e - EAA - EDD - EAD - EAB;
    int s = db[i], d = db[EDB + i];
    int pos = atomicAdd(&st[S_CUR_DB + d], 1);
    st[S_SRC_DB + pos] = s;
  }
}

// ---------------- projection (K=16) -> bf16 P ----------------
__global__ __launch_bounds__(128) void proj_kernel(
    const float* __restrict__ xa, const float* __restrict__ xd, const float* __restrict__ xb,
    const float* __restrict__ Wpa, const float* __restrict__ bpa,
    const float* __restrict__ Wpd, const float* __restrict__ bpd,
    const float* __restrict__ Wpb, const float* __restrict__ bpb,
    unsigned short* __restrict__ Pb) {
  int b = blockIdx.x;
  int t = b / NTT, n = b % NTT;
  const float *x, *W, *bias;
  int row;
  if (n < 1024)      { x = xa; W = Wpa; bias = bpa; row = t * 1024 + n; }
  else if (n < 2048) { x = xd; W = Wpd; bias = bpd; row = t * 1024 + (n - 1024); }
  else               { x = xb; W = Wpb; bias = bpb; row = t * 128  + (n - 2048); }
  __shared__ float xr[16];
  if (threadIdx.x < 16) xr[threadIdx.x] = x[(size_t)row * 16 + threadIdx.x];
  __syncthreads();
  int c = threadIdx.x;
  float acc = bias[c];
#pragma unroll
  for (int k = 0; k < 16; ++k) acc = fmaf(xr[k], W[k * 128 + c], acc);
  Pb[((size_t)t * NTT + n) * 128 + c] = f2b(acc);
}

// ---------------- GNN weight prep: WT[m][n][k] bf16 ----------------
__global__ __launch_bounds__(256) void gnn_wt_build(
    const float* __restrict__ Wg_aa, const float* __restrict__ Wg_dd,
    const float* __restrict__ Wl_ad, const float* __restrict__ Wr_ad,
    const float* __restrict__ Wl_ab, const float* __restrict__ Wl_db,
    const float* __restrict__ Wr_ab, const float* __restrict__ Wr_db,
    const float* __restrict__ bg_aa, const float* __restrict__ bg_dd,
    const float* __restrict__ bl_ad, const float* __restrict__ bl_ab,
    const float* __restrict__ bl_db,
    unsigned short* __restrict__ WTg, float* __restrict__ BT) {
  int m = blockIdx.x;
  const float* Ws[7] = {Wg_aa, Wg_dd, Wl_ad, Wr_ad, Wl_ab, Wl_db, Wr_ab};
  const float* W1 = Ws[m];
  for (int idx = threadIdx.x; idx < 16384; idx += 256) {
    int n = idx >> 7, k = idx & 127;
    float v = W1[k * 128 + n];
    if (m == 6) v += Wr_db[k * 128 + n];   // combined WrB = Wr_ab + Wr_db
    WTg[(size_t)m * 16384 + n * 128 + k] = f2b(v);
  }
  if (m == 0 && threadIdx.x < 128) {
    int n = threadIdx.x;
    BT[n]       = bg_aa[n];
    BT[128 + n] = bg_dd[n] + bl_ad[n];
    BT[256 + n] = bl_ab[n] + bl_db[n];
  }
}

// ---------------- fused GNN helpers ----------------
__device__ __forceinline__ void gather_agg(
    const unsigned short* __restrict__ Psrc,
    const int* __restrict__ offs, const int* __restrict__ ssrc,
    const float* __restrict__ snorm, const float* __restrict__ inv,
    int dbase, unsigned short AGG[64][136], int tid) {
  int d_local = tid >> 2;
  int cg = (tid & 3) << 5;
  int d = dbase + d_local;
  int e0 = offs[d], e1 = offs[d + 1];
  float a[32];
#pragma unroll
  for (int j = 0; j < 32; ++j) a[j] = 0.f;
  const unsigned short* pbase = Psrc + cg;
  for (int e = e0; e < e1; ++e) {
    int s = ssrc[e];
    float sc = snorm ? snorm[e] : 1.0f;
    const unsigned short* pr = pbase + (size_t)s * 128;
#pragma unroll
    for (int c = 0; c < 4; ++c) {
      bf16x8 v = *(const bf16x8*)(pr + c * 8);
#pragma unroll
      for (int i = 0; i < 8; ++i)
        a[c * 8 + i] = fmaf(b2f((unsigned short)v[i]), sc, a[c * 8 + i]);
    }
  }
  float scale = inv ? inv[d] : 1.0f;
#pragma unroll
  for (int j = 0; j < 16; ++j) {
    unsigned int pk = (unsigned int)f2b(a[2 * j] * scale)
                    | ((unsigned int)f2b(a[2 * j + 1] * scale) << 16);
    *(unsigned int*)&AGG[d_local][cg + 2 * j] = pk;
  }
}

__device__ __forceinline__ void mfma_agg(
    const unsigned short AGG[64][136], const unsigned short* __restrict__ wt,
    f32x4 acc[8], int w, int l15, int lk) {
#pragma unroll
  for (int ks = 0; ks < 4; ++ks) {
    int k = ks * 32 + lk;
    bf16x8 af = *(const bf16x8*)&AGG[w * 16 + l15][k];
#pragma unroll
    for (int f = 0; f < 8; ++f) {
      bf16x8 bfr = *(const bf16x8*)(wt + (size_t)(f * 16 + l15) * 128 + k);
      acc[f] = __builtin_amdgcn_mfma_f32_16x16x32_bf16(af, bfr, acc[f], 0, 0, 0);
    }
  }
}

__device__ __forceinline__ void mfma_direct(
    const unsigned short* __restrict__ prow, const unsigned short* __restrict__ wt,
    f32x4 acc[8], int l15, int lk) {
#pragma unroll
  for (int ks = 0; ks < 4; ++ks) {
    int k = ks * 32 + lk;
    bf16x8 af = *(const bf16x8*)(prow + k);
#pragma unroll
    for (int f = 0; f < 8; ++f) {
      bf16x8 bfr = *(const bf16x8*)(wt + (size_t)(f * 16 + l15) * 128 + k);
      acc[f] = __builtin_amdgcn_mfma_f32_16x16x32_bf16(af, bfr, acc[f], 0, 0, 0);
    }
  }
}

// ---------------- fused GNN: per (frame, 64-row slice) block, writes Zb bf16 ----------------
// XCD-affinity swizzle: all 34 blocks of a frame land on one XCD (HW heuristic: xcd = wgid % 8)
__global__ __launch_bounds__(256) void gnn_fused(
    const unsigned short* __restrict__ Pb, unsigned short* __restrict__ Zb,
    const unsigned short* __restrict__ WTg, const float* __restrict__ BT,
    const int* __restrict__ st) {
  const float* stf = (const float*)st;
  int L = blockIdx.x;
  int slot = L >> 3;                       // 0..203
  int t = (L & 7) + ((slot / 34) << 3);    // frames {xcd, xcd+8, ..., xcd+40}
  int rb = slot % 34;
  int row0 = rb * 64;
  int tid = threadIdx.x;
  int w = tid >> 6, lane = tid & 63, l15 = lane & 15, lk = (lane >> 4) * 8;

  __shared__ unsigned short AGG[64][136];

  int typ = (rb < 16) ? 0 : (rb < 32 ? 1 : 2);
  const float* bias = BT + typ * 128;
  f32x4 acc[8];
#pragma unroll
  for (int f = 0; f < 8; ++f) {
    float b = bias[f * 16 + l15];
    f32x4 bv = {b, b, b, b};
    acc[f] = bv;
  }

  const unsigned short* Pt = Pb + (size_t)t * NTT * 128;
  const unsigned short* prowD = Pt + (size_t)(row0 + w * 16 + l15) * 128;

  if (typ == 0) {
    gather_agg(Pt, st + S_OFF_AA, st + S_SRC_AA, stf + S_NRM_AA, nullptr, row0, AGG, tid);
    __syncthreads();
    mfma_agg(AGG, WTg + 0 * 16384, acc, w, l15, lk);
  } else if (typ == 1) {
    int dbase = row0 - 1024;
    gather_agg(Pt + 1024 * 128, st + S_OFF_DD, st + S_SRC_DD, stf + S_NRM_DD, nullptr, dbase, AGG, tid);
    __syncthreads();
    mfma_agg(AGG, WTg + 1 * 16384, acc, w, l15, lk);
    __syncthreads();
    gather_agg(Pt, st + S_OFF_AD, st + S_SRC_AD, nullptr, stf + S_INV_AD, dbase, AGG, tid);
    __syncthreads();
    mfma_agg(AGG, WTg + 2 * 16384, acc, w, l15, lk);
    mfma_direct(prowD, WTg + 3 * 16384, acc, l15, lk);
  } else {
    int dbase = row0 - 2048;
    gather_agg(Pt, st + S_OFF_AB, st + S_SRC_AB, nullptr, stf + S_INV_AB, dbase, AGG, tid);
    __syncthreads();
    mfma_agg(AGG, WTg + 4 * 16384, acc, w, l15, lk);
    __syncthreads();
    gather_agg(Pt + 1024 * 128, st + S_OFF_DB, st + S_SRC_DB, nullptr, stf + S_INV_DB, dbase, AGG, tid);
    __syncthreads();
    mfma_agg(AGG, WTg + 5 * 16384, acc, w, l15, lk);
    mfma_direct(prowD, WTg + 6 * 16384, acc, l15, lk);
  }

  __syncthreads();
#pragma unroll
  for (int f = 0; f < 8; ++f) {
#pragma unroll
    for (int q = 0; q < 4; ++q) {
      int rl = w * 16 + (lane >> 4) * 4 + q;
      AGG[rl][f * 16 + l15] = f2b(acc[f][q]);
    }
  }
  __syncthreads();
  unsigned short* zt = Zb + ((size_t)t * NTT + row0) * 128;
  for (int idx = tid; idx < 1024; idx += 256) {
    int r = idx >> 4, c = (idx & 15) << 3;
    *(uint4*)(zt + (size_t)r * 128 + c) = *(const uint4*)&AGG[r][c];
  }
}

// ---------------- GRU setup: permuted+transposed bf16 weights, fused biases ----------------
// WcT[p][k], p = triple*48 + g*16 + cc; orig col = g*256 + triple*16 + cc; k<128 Wi, else Wh
__global__ __launch_bounds__(384) void wct_build(
    const float* __restrict__ Wi, const float* __restrict__ Wh,
    const float* __restrict__ bi, const float* __restrict__ bh,
    unsigned short* __restrict__ WcT, float* __restrict__ BA, float* __restrict__ BB) {
  int p = blockIdx.x;
  int k = threadIdx.x;
  int triple = p / 48, g = (p % 48) / 16, cc = p % 16;
  int orig = g * 256 + triple * 16 + cc;
  float w = (k < 128) ? Wi[(size_t)k * GG + orig] : Wh[(size_t)(k - 128) * GG + orig];
  WcT[(size_t)p * 384 + k] = f2b(w);
  if (k == 0) {
    BA[p] = (g < 2) ? (bi[orig] + bh[orig]) : bi[orig];
    BB[p] = bh[orig];
  }
}

// ---------------- persistent GRU: 136 blocks x 16 nodes, all 48 steps in-kernel ----------------
// wave w owns gate cols [192w, 192w+192) = triples 4w..4w+3.
// Wh k in [128,320): 288 VGPRs/wave.  Wh k in [320,384): LDS slab (XOR-swizzled).
// Wi (k<128): streamed from L2 each step (196 KB, L2-hot).  h: LDS + regs.
__global__ __launch_bounds__(256, 1) void gru_persist(
    const unsigned short* __restrict__ Zb,
    const unsigned short* __restrict__ WcT,
    const float* __restrict__ BA, const float* __restrict__ BB,
    unsigned short* __restrict__ Hout) {
  __shared__ unsigned short WL[768 * 64];   // k in [320,384), 16B-chunk XOR swizzle by (p&7)
  __shared__ unsigned short HS[16][264];    // h state, padded stride (2-way bank = free)

  const int tid = threadIdx.x;
  const int w = tid >> 6;
  const int lane = tid & 63;
  const int l15 = lane & 15;
  const int lk = (lane >> 4) << 3;
  const int node0 = blockIdx.x * 16;
  const int pbase = w * 192;
  const int qrow = (lane >> 4) << 2;
  const int swz = l15 & 7;

  // load WL cooperatively (swizzled)
  for (int idx = tid; idx < 768 * 8; idx += 256) {
    int p = idx >> 3, ch = idx & 7;
    *(bf16x8*)&WL[p * 64 + ((ch ^ (p & 7)) << 3)] =
        *(const bf16x8*)(WcT + (size_t)p * 384 + 320 + ch * 8);
  }
  for (int idx = tid; idx < 16 * 264; idx += 256) ((unsigned short*)HS)[idx] = 0;

  // persistent Wh regs: kt 0..5 -> k 128..319
  bf16x8 wreg[12][6];
#pragma unroll
  for (int ct = 0; ct < 12; ++ct)
#pragma unroll
    for (int kt = 0; kt < 6; ++kt)
      wreg[ct][kt] = *(const bf16x8*)(WcT + (size_t)(pbase + ct * 16 + l15) * 384 + 128 + kt * 32 + lk);

  float bar[4], baz[4], ban[4], bbn[4];
#pragma unroll
  for (int tr = 0; tr < 4; ++tr) {
    int pt = pbase + tr * 48 + l15;
    bar[tr] = BA[pt]; baz[tr] = BA[pt + 16]; ban[tr] = BA[pt + 32]; bbn[tr] = BB[pt + 32];
  }

  float hold[4][4];
#pragma unroll
  for (int tr = 0; tr < 4; ++tr)
#pragma unroll
    for (int q = 0; q < 4; ++q) hold[tr][q] = 0.f;

  __syncthreads();

#pragma unroll 1
  for (int t = 0; t < TT; ++t) {
    // opaque zero offsets: block LICM from hoisting per-step loads into 190+ regs
    size_t tinv = 0;
    int tinv32 = 0;
    asm volatile("" : "+s"(tinv), "+s"(tinv32));

    f32x4 accR[4], accZ[4], accNi[4], accNh[4];
#pragma unroll
    for (int tr = 0; tr < 4; ++tr) {
      f32x4 z4 = {0.f, 0.f, 0.f, 0.f};
      accR[tr] = z4; accZ[tr] = z4; accNi[tr] = z4; accNh[tr] = z4;
    }

    // ---- z-part: K 0..127, A from global Zb, B (Wi) streamed from L2 ----
    const unsigned short* zt = Zb + ((size_t)t * NTT + node0) * 128;
    const unsigned short* WcTz = WcT + tinv;
#pragma unroll
    for (int kt = 0; kt < 4; ++kt) {
      bf16x8 a = *(const bf16x8*)(zt + (size_t)l15 * 128 + kt * 32 + lk);
#pragma unroll
      for (int ct = 0; ct < 12; ++ct) {
        bf16x8 b = *(const bf16x8*)(WcTz + (size_t)(pbase + ct * 16 + l15) * 384 + kt * 32 + lk);
        int tr = ct / 3, g = ct % 3;
        if (g == 0)      accR[tr]  = __builtin_amdgcn_mfma_f32_16x16x32_bf16(a, b, accR[tr], 0, 0, 0);
        else if (g == 1) accZ[tr]  = __builtin_amdgcn_mfma_f32_16x16x32_bf16(a, b, accZ[tr], 0, 0, 0);
        else             accNi[tr] = __builtin_amdgcn_mfma_f32_16x16x32_bf16(a, b, accNi[tr], 0, 0, 0);
      }
    }

    // ---- h-part: K 128..383, A from LDS h, B from regs (kt<6) / LDS slab (kt 6,7) ----
#pragma unroll
    for (int kt = 0; kt < 8; ++kt) {
      bf16x8 a = *(const bf16x8*)&HS[l15][kt * 32 + lk];
#pragma unroll
      for (int ct = 0; ct < 12; ++ct) {
        bf16x8 b;
        if (kt < 6) {
          b = wreg[ct][kt];
        } else {
          int ch = ((kt - 6) << 2) + (lk >> 3);
          b = *(const bf16x8*)&WL[(pbase + ct * 16 + l15) * 64 + ((ch ^ swz) << 3) + tinv32];
        }
        int tr = ct / 3, g = ct % 3;
        if (g == 0)      accR[tr]  = __builtin_amdgcn_mfma_f32_16x16x32_bf16(a, b, accR[tr], 0, 0, 0);
        else if (g == 1) accZ[tr]  = __builtin_amdgcn_mfma_f32_16x16x32_bf16(a, b, accZ[tr], 0, 0, 0);
        else             accNh[tr] = __builtin_amdgcn_mfma_f32_16x16x32_bf16(a, b, accNh[tr], 0, 0, 0);
      }
    }

    __syncthreads();   // all waves done reading HS

    // ---- gates + h update (C/D: col=l&15, row=(l>>4)*4+q) ----
#pragma unroll
    for (int tr = 0; tr < 4; ++tr) {
      int hcol = w * 64 + tr * 16 + l15;
#pragma unroll
      for (int q = 0; q < 4; ++q) {
        float rr = 1.f / (1.f + __expf(-(accR[tr][q] + bar[tr])));
        float zz = 1.f / (1.f + __expf(-(accZ[tr][q] + baz[tr])));
        float x2 = 2.f * (accNi[tr][q] + ban[tr] + rr * (accNh[tr][q] + bbn[tr]));
        float nn = 1.f - 2.f / (__expf(x2) + 1.f);     // tanh
        float hn = (1.f - zz) * nn + zz * hold[tr][q];
        unsigned short hb = f2b(hn);
        hold[tr][q] = b2f(hb);
        HS[qrow + q][hcol] = hb;
      }
    }
    __syncthreads();   // new h visible
  }

  // final h -> global
#pragma unroll
  for (int tr = 0; tr < 4; ++tr)
#pragma unroll
    for (int q = 0; q < 4; ++q)
      Hout[(size_t)(node0 + qrow + q) * 256 + w * 64 + tr * 16 + l15] = f2b(hold[tr][q]);
}

// ---------------- pooling (two-stage) + final projection ----------------
__global__ __launch_bounds__(256) void pool_part(const unsigned short* __restrict__ Hb,
                                                 float* __restrict__ part) {
  int blk = blockIdx.x;
  int j = threadIdx.x;
  int base = blk * 64;
  float s = 0.f;
  for (int r = 0; r < 64; ++r) s += b2f(Hb[(size_t)(base + r) * 256 + j]);
  part[blk * 256 + j] = s;
}

__global__ __launch_bounds__(256) void pool_final(const float* __restrict__ part,
                                                  float* __restrict__ pooled) {
  int typ = blockIdx.x;
  int j = threadIdx.x;
  int b0 = (typ == 0) ? 0 : (typ == 1 ? 16 : 32);
  int b1 = (typ == 2) ? 34 : b0 + 16;
  float s = 0.f;
  for (int b = b0; b < b1; ++b) s += part[b * 256 + j];
  pooled[typ * 256 + j] = s / (float)((typ == 2) ? 128 : 1024);
}

__global__ __launch_bounds__(128) void out_kernel(
    const float* __restrict__ pooled, const float* __restrict__ Wout,
    const float* __restrict__ bout, float* __restrict__ out) {
  int o = threadIdx.x;
  float acc = bout[o];
  for (int g = 0; g < GG; ++g) acc = fmaf(pooled[g], Wout[g * 128 + o], acc);
  out[o] = acc;
}

// ---------------- host launcher ----------------
extern "C" void kernel_launch(void* const* d_in, const int* in_sizes, int n_in,
                              void* d_out, int out_size, void* d_ws, size_t ws_size,
                              hipStream_t stream) {
  const float* xa    = (const float*)d_in[0];
  const float* xd    = (const float*)d_in[1];
  const float* xb    = (const float*)d_in[2];
  const int*   ei_aa = (const int*)d_in[3];
  const int*   ei_ad = (const int*)d_in[4];
  const int*   ei_dd = (const int*)d_in[5];
  const int*   ei_ab = (const int*)d_in[6];
  const int*   ei_db = (const int*)d_in[7];
  const float* Wp_a = (const float*)d_in[8];  const float* bp_a = (const float*)d_in[9];
  const float* Wp_d = (const float*)d_in[10]; const float* bp_d = (const float*)d_in[11];
  const float* Wp_b = (const float*)d_in[12]; const float* bp_b = (const float*)d_in[13];
  const float* Wg_aa = (const float*)d_in[14]; const float* bg_aa = (const float*)d_in[15];
  const float* Wg_dd = (const float*)d_in[16]; const float* bg_dd = (const float*)d_in[17];
  const float* Wl_ad = (const float*)d_in[18]; const float* Wr_ad = (const float*)d_in[19];
  const float* bl_ad = (const float*)d_in[20];
  const float* Wl_ab = (const float*)d_in[21]; const float* Wr_ab = (const float*)d_in[22];
  const float* bl_ab = (const float*)d_in[23];
  const float* Wl_db = (const float*)d_in[24]; const float* Wr_db = (const float*)d_in[25];
  const float* bl_db = (const float*)d_in[26];
  const float* Wi   = (const float*)d_in[27]; const float* Wh   = (const float*)d_in[28];
  const float* bi   = (const float*)d_in[29]; const float* bh   = (const float*)d_in[30];
  const float* Wout = (const float*)d_in[31]; const float* bout = (const float*)d_in[32];

  float* ws   = (float*)d_ws;
  unsigned short* Pb  = (unsigned short*)(ws + OFF_PB);
  unsigned short* Zb  = (unsigned short*)(ws + OFF_ZB);
  unsigned short* H0  = (unsigned short*)(ws + OFF_H0);
  unsigned short* WcT = (unsigned short*)(ws + OFF_WCT);
  float* BA = ws + OFF_BA;
  float* BB = ws + OFF_BB;
  unsigned short* WTg = (unsigned short*)(ws + OFF_WTG);
  float* BT = ws + OFF_BT;
  float* pooled = ws + OFF_POOL;
  float* part   = ws + OFF_PART;
  int*   st  = (int*)(ws + OFF_STATS);

  hipMemsetAsync(st, 0, (size_t)S_ZERO_END * 4, stream);

  // --- CSR build (3 kernels) ---
  count_all<<<NEDGE / 256, 256, 0, stream>>>(ei_aa, ei_dd, ei_ad, ei_ab, ei_db, st);
  scan5<<<5, 1024, 0, stream>>>(st);
  fill_all<<<NEDGE / 256, 256, 0, stream>>>(ei_aa, ei_dd, ei_ad, ei_ab, ei_db, st);

  // --- projections (bf16) + weight prep ---
  proj_kernel<<<TT * NTT, 128, 0, stream>>>(xa, xd, xb, Wp_a, bp_a, Wp_d, bp_d, Wp_b, bp_b, Pb);
  gnn_wt_build<<<7, 256, 0, stream>>>(Wg_aa, Wg_dd, Wl_ad, Wr_ad, Wl_ab, Wl_db, Wr_ab, Wr_db,
                                      bg_aa, bg_dd, bl_ad, bl_ab, bl_db, WTg, BT);
  wct_build<<<GG, 384, 0, stream>>>(Wi, Wh, bi, bh, WcT, BA, BB);

  // --- fused GNN: Pb -> Zb (XCD frame affinity) ---
  gnn_fused<<<TT * 34, 256, 0, stream>>>(Pb, Zb, WTg, BT, st);

  // --- persistent GRU: all 48 steps in one launch ---
  gru_persist<<<NTT / 16, 256, 0, stream>>>(Zb, WcT, BA, BB, H0);

  // --- pool + output ---
  pool_part<<<34, 256, 0, stream>>>(H0, part);
  pool_final<<<3, 256, 0, stream>>>(part, pooled);
  out_kernel<<<1, 128, 0, stream>>>(pooled, Wout, bout, (float*)d_out);
}